// Round 8
// baseline (326.656 us; speedup 1.0000x reference)
//
#include <hip/hip_runtime.h>
#include <hip/hip_bf16.h>
#include <math.h>

#define DMODEL 1024
#define NH 16
#define HD 64
#define SEQ 2048
#define BATCH 2
#define MROWS (BATCH * SEQ)   // 4096
#define FFN_DIM 4096

using bf16x8 = __attribute__((ext_vector_type(8))) __bf16;
using f32x4  = __attribute__((ext_vector_type(4))) float;

typedef const __attribute__((address_space(1))) unsigned char* gas_t;
typedef __attribute__((address_space(3))) unsigned char* las_t;

__device__ inline unsigned short f2bf(float f) {
    unsigned int u = __builtin_bit_cast(unsigned int, f);
    u += 0x7fffu + ((u >> 16) & 1u);   // round-to-nearest-even
    return (unsigned short)(u >> 16);
}
__device__ inline unsigned short f2bf_up(float f) {
    unsigned int u = __builtin_bit_cast(unsigned int, f);
    return (unsigned short)((u + 0x8000u) >> 16);
}
__device__ inline float bf2f(unsigned short u) {
    unsigned int v = ((unsigned int)u) << 16;
    return __builtin_bit_cast(float, v);
}
// tanh-GELU (branch-free): x * sigmoid(1.59577x + 0.0713548x^3); |err| <= ~3e-3
__device__ inline float gelu_f(float x) {
    float x2 = x * x;
    float w = x * fmaf(0.07135481627f, x2, 1.59576912161f);
    return x / (1.0f + __expf(-w));
}

// ---------------- fused: pre-LayerNorm (blocks < MROWS) + weight cvt (rest) ----------------
// qkv/fc1 weights -> bf16; fc2 weights -> fp8 via HW packed cvt
__global__ __launch_bounds__(256) void ln_pre_cvt(
        const float* __restrict__ a,
        const float* __restrict__ gamma, const float* __restrict__ beta,
        float* __restrict__ out_f, unsigned short* __restrict__ out_b,
        const float* __restrict__ wa, unsigned short* __restrict__ oa, int na4,
        const float* __restrict__ wb, unsigned short* __restrict__ ob, int nb4,
        const float* __restrict__ wc, unsigned char* __restrict__ oc, int nc4) {
    int blk = blockIdx.x;
    int t = threadIdx.x;
    if (blk >= MROWS) {
        int i = (blk - MROWS) * 256 + t;
        if (i < na4) {
            float4 v = ((const float4*)wa)[i];
            ushort4 o;
            o.x = f2bf(v.x); o.y = f2bf(v.y); o.z = f2bf(v.z); o.w = f2bf(v.w);
            ((ushort4*)oa)[i] = o;
        } else if (i < na4 + nb4) {
            int j = i - na4;
            float4 v = ((const float4*)wb)[j];
            ushort4 o;
            o.x = f2bf(v.x); o.y = f2bf(v.y); o.z = f2bf(v.z); o.w = f2bf(v.w);
            ((ushort4*)ob)[j] = o;
        } else if (i < na4 + nb4 + nc4) {
            int j = i - na4 - nb4;
            float4 v = ((const float4*)wc)[j];
            int pk = __builtin_amdgcn_cvt_pk_fp8_f32(v.x, v.y, 0, false);
            pk     = __builtin_amdgcn_cvt_pk_fp8_f32(v.z, v.w, pk, true);
            ((unsigned int*)oc)[j] = (unsigned int)pk;
        }
        return;
    }
    int row = blk;
    float4 v = ((const float4*)(a + (size_t)row * DMODEL))[t];
    float s  = v.x + v.y + v.z + v.w;
    float s2 = v.x * v.x + v.y * v.y + v.z * v.z + v.w * v.w;
    #pragma unroll
    for (int off = 32; off > 0; off >>= 1) {
        s  += __shfl_xor(s,  off, 64);
        s2 += __shfl_xor(s2, off, 64);
    }
    __shared__ float red[8];
    int wave = t >> 6, lane = t & 63;
    if (lane == 0) { red[wave] = s; red[4 + wave] = s2; }
    __syncthreads();
    float tot  = red[0] + red[1] + red[2] + red[3];
    float tot2 = red[4] + red[5] + red[6] + red[7];
    float mu   = tot * (1.0f / DMODEL);
    float var  = tot2 * (1.0f / DMODEL) - mu * mu;
    float rstd = rsqrtf(var + 1e-5f);
    float4 g  = ((const float4*)gamma)[t];
    float4 be = ((const float4*)beta)[t];
    float4 o;
    o.x = (v.x - mu) * rstd * g.x + be.x;
    o.y = (v.y - mu) * rstd * g.y + be.y;
    o.z = (v.z - mu) * rstd * g.z + be.z;
    o.w = (v.w - mu) * rstd * g.w + be.w;
    ((float4*)(out_f + (size_t)row * DMODEL))[t] = o;
    ushort4 ob4;
    ob4.x = f2bf(o.x); ob4.y = f2bf(o.y); ob4.z = f2bf(o.z); ob4.w = f2bf(o.w);
    ((ushort4*)(out_b + (size_t)row * DMODEL))[t] = ob4;
}

// ---------------- AddNorm1 fused with attention combine ----------------
__global__ __launch_bounds__(256) void ln_attn(
        const float* __restrict__ o0, const float* __restrict__ o1,
        const float* __restrict__ l0, const float* __restrict__ l1,
        const float* __restrict__ xres,
        const float* __restrict__ gamma, const float* __restrict__ beta,
        float* __restrict__ out_f, unsigned short* __restrict__ out_b) {
    int row = blockIdx.x;
    int t = threadIdx.x;
    int b_ = row >> 11, s = row & 2047;
    int h = t >> 4;
    int bh = b_ * NH + h;
    size_t obase = ((size_t)bh * SEQ + s) * HD + (4 * t & 63);
    float4 va = ((const float4*)(o0 + obase))[0];
    float4 vb = ((const float4*)(o1 + obase))[0];
    float inv_l = 1.0f / (l0[(size_t)bh * SEQ + s] + l1[(size_t)bh * SEQ + s]);
    float4 rr = ((const float4*)(xres + (size_t)row * DMODEL))[t];
    float4 v;
    v.x = (va.x + vb.x) * inv_l + rr.x;
    v.y = (va.y + vb.y) * inv_l + rr.y;
    v.z = (va.z + vb.z) * inv_l + rr.z;
    v.w = (va.w + vb.w) * inv_l + rr.w;

    float s1 = v.x + v.y + v.z + v.w;
    float s2 = v.x * v.x + v.y * v.y + v.z * v.z + v.w * v.w;
    #pragma unroll
    for (int off = 32; off > 0; off >>= 1) {
        s1 += __shfl_xor(s1, off, 64);
        s2 += __shfl_xor(s2, off, 64);
    }
    __shared__ float red[8];
    int wave = t >> 6, lane = t & 63;
    if (lane == 0) { red[wave] = s1; red[4 + wave] = s2; }
    __syncthreads();
    float tot  = red[0] + red[1] + red[2] + red[3];
    float tot2 = red[4] + red[5] + red[6] + red[7];
    float mu   = tot * (1.0f / DMODEL);
    float var  = tot2 * (1.0f / DMODEL) - mu * mu;
    float rstd = rsqrtf(var + 1e-5f);
    float4 g  = ((const float4*)gamma)[t];
    float4 be = ((const float4*)beta)[t];
    float4 o;
    o.x = (v.x - mu) * rstd * g.x + be.x;
    o.y = (v.y - mu) * rstd * g.y + be.y;
    o.z = (v.z - mu) * rstd * g.z + be.z;
    o.w = (v.w - mu) * rstd * g.w + be.w;
    ((float4*)(out_f + (size_t)row * DMODEL))[t] = o;
    ushort4 ob;
    ob.x = f2bf(o.x); ob.y = f2bf(o.y); ob.z = f2bf(o.z); ob.w = f2bf(o.w);
    ((ushort4*)(out_b + (size_t)row * DMODEL))[t] = ob;
}

// ---------------- AddNorm fused with split-K reduction (FC2 epilogue) ----------------
__global__ __launch_bounds__(256) void ln_fc2(
        const unsigned short* __restrict__ p0, const unsigned short* __restrict__ p1,
        const unsigned short* __restrict__ p2, const unsigned short* __restrict__ p3,
        const float* __restrict__ bias, const float* __restrict__ resid,
        const float* __restrict__ gamma, const float* __restrict__ beta,
        float* __restrict__ out_f) {
    int row = blockIdx.x;
    int t = threadIdx.x;
    size_t base = (size_t)row * DMODEL;
    ushort4 u0 = ((const ushort4*)(p0 + base))[t];
    ushort4 u1 = ((const ushort4*)(p1 + base))[t];
    ushort4 u2 = ((const ushort4*)(p2 + base))[t];
    ushort4 u3 = ((const ushort4*)(p3 + base))[t];
    float4 bb = ((const float4*)bias)[t];
    float4 rr = ((const float4*)(resid + base))[t];
    float4 v;
    v.x = bf2f(u0.x) + bf2f(u1.x) + bf2f(u2.x) + bf2f(u3.x) + bb.x + rr.x;
    v.y = bf2f(u0.y) + bf2f(u1.y) + bf2f(u2.y) + bf2f(u3.y) + bb.y + rr.y;
    v.z = bf2f(u0.z) + bf2f(u1.z) + bf2f(u2.z) + bf2f(u3.z) + bb.z + rr.z;
    v.w = bf2f(u0.w) + bf2f(u1.w) + bf2f(u2.w) + bf2f(u3.w) + bb.w + rr.w;

    float s  = v.x + v.y + v.z + v.w;
    float s2 = v.x * v.x + v.y * v.y + v.z * v.z + v.w * v.w;
    #pragma unroll
    for (int off = 32; off > 0; off >>= 1) {
        s  += __shfl_xor(s,  off, 64);
        s2 += __shfl_xor(s2, off, 64);
    }
    __shared__ float red[8];
    int wave = t >> 6, lane = t & 63;
    if (lane == 0) { red[wave] = s; red[4 + wave] = s2; }
    __syncthreads();
    float tot  = red[0] + red[1] + red[2] + red[3];
    float tot2 = red[4] + red[5] + red[6] + red[7];
    float mu   = tot * (1.0f / DMODEL);
    float var  = tot2 * (1.0f / DMODEL) - mu * mu;
    float rstd = rsqrtf(var + 1e-5f);
    float4 g  = ((const float4*)gamma)[t];
    float4 be = ((const float4*)beta)[t];
    float4 o;
    o.x = (v.x - mu) * rstd * g.x + be.x;
    o.y = (v.y - mu) * rstd * g.y + be.y;
    o.z = (v.z - mu) * rstd * g.z + be.z;
    o.w = (v.w - mu) * rstd * g.w + be.w;
    ((float4*)(out_f + base))[t] = o;
}

// ---------------- bf16 NT GEMM: 3-buffer depth-2 counted-vmcnt pipeline (BK=32) --------
// fp8 kernel's validated memory skeleton at 64B/row: 8KB buffers, srow0=tid>>2,
// schunk=tid&3, swizzle g=chunk^((row>>1)&3), vmcnt(4) steady-state, lgkmcnt(0)
// before each s_barrier, vmcnt(0) only at tail. 48KB LDS -> 3 blocks/CU (was 2).
// Each old K=64 step = two K=32 steps issuing the SAME two MFMAs in the same
// order per acc element -> bit-identical numerics.
// MODE 1: bias+GELU(tanh) -> fp8 out.  MODE 3: qkv scatter bf16 (q pre-scaled).
template <int MODE>
__global__ __launch_bounds__(256) void gemm_lds(
        const unsigned short* __restrict__ A,
        const unsigned short* __restrict__ Bw,
        const float* __restrict__ bias,
        void* __restrict__ out, int M, int N, int K) {
    __shared__ unsigned short As[3][128 * 32];   // 3 x 8 KB
    __shared__ unsigned short Bs[3][128 * 32];   // 3 x 8 KB

    const int tid  = threadIdx.x;
    const int wave = tid >> 6;
    const int lane = tid & 63;
    const int quad = lane >> 4;
    const int cc   = lane & 15;
    const int bn = blockIdx.x * 128;
    const int bm = blockIdx.y * 128;

    const unsigned short* Ab = A  + (size_t)bm * K;
    const unsigned short* Bb = Bw + (size_t)bn * K;

    const int srow0  = tid >> 2;         // 0..63
    const int schunk = tid & 3;          // 16B chunk within 64B row
    const int rsw    = (cc >> 1) & 3;    // read swizzle: (row>>1)&3 with row=16a+cc
    const int wm = (wave >> 1) * 64;
    const int wn = (wave & 1) * 64;

    f32x4 acc[4][4] = {};

    auto stage = [&](int buf, int k0) {
        #pragma unroll
        for (int i = 0; i < 2; ++i) {
            int row = i * 64 + srow0;
            int g   = schunk ^ ((row >> 1) & 3);
            const unsigned short* ga = Ab + (size_t)row * K + k0 + g * 8;
            const unsigned short* gb = Bb + (size_t)row * K + k0 + g * 8;
            unsigned short* la = &As[buf][i * 2048 + wave * 512];
            unsigned short* lb = &Bs[buf][i * 2048 + wave * 512];
            __builtin_amdgcn_global_load_lds((gas_t)(const void*)ga, (las_t)(void*)la, 16, 0, 0);
            __builtin_amdgcn_global_load_lds((gas_t)(const void*)gb, (las_t)(void*)lb, 16, 0, 0);
        }
    };

    const int nkt = K >> 5;   // 32 for K=1024
    stage(0, 0);
    if (nkt > 1) {
        stage(1, 32);
        asm volatile("s_waitcnt vmcnt(4)" ::: "memory");   // buf0 landed; buf1 in flight
    } else {
        asm volatile("s_waitcnt vmcnt(0)" ::: "memory");
    }
    __builtin_amdgcn_s_barrier();

    int cur = 0;
    for (int kt = 0; kt < nkt; ++kt) {
        int pbuf = cur + 2; if (pbuf >= 3) pbuf -= 3;      // (cur+2)%3
        if (kt + 2 < nkt) stage(pbuf, (kt + 2) << 5);

        bf16x8 af[4], bf[4];
        #pragma unroll
        for (int mt = 0; mt < 4; ++mt)
            af[mt] = *(const bf16x8*)&As[cur][(wm + mt * 16 + cc) * 32 + ((quad ^ rsw) * 8)];
        #pragma unroll
        for (int nt = 0; nt < 4; ++nt)
            bf[nt] = *(const bf16x8*)&Bs[cur][(wn + nt * 16 + cc) * 32 + ((quad ^ rsw) * 8)];

        #pragma unroll
        for (int mt = 0; mt < 4; ++mt)
            #pragma unroll
            for (int nt = 0; nt < 4; ++nt)
                acc[mt][nt] = __builtin_amdgcn_mfma_f32_16x16x32_bf16(
                    af[mt], bf[nt], acc[mt][nt], 0, 0, 0);

        if (kt + 1 < nkt) {
            asm volatile("s_waitcnt lgkmcnt(0)" ::: "memory");   // my LDS reads done
            if (kt + 2 < nkt)
                asm volatile("s_waitcnt vmcnt(4)" ::: "memory"); // kt+1 landed; kt+2 in flight
            else
                asm volatile("s_waitcnt vmcnt(0)" ::: "memory"); // tail: drain final tile
            __builtin_amdgcn_s_barrier();
        }
        cur = (cur < 2) ? cur + 1 : 0;
    }

    #pragma unroll
    for (int mt = 0; mt < 4; ++mt)
        #pragma unroll
        for (int nt = 0; nt < 4; ++nt) {
            if constexpr (MODE == 1) {
                int m0 = bm + wm + mt * 16 + quad * 4;
                int n  = bn + wn + nt * 16 + cc;
                float bn_ = bias[n];
                float v0 = gelu_f(acc[mt][nt][0] + bn_);
                float v1 = gelu_f(acc[mt][nt][1] + bn_);
                float v2 = gelu_f(acc[mt][nt][2] + bn_);
                float v3 = gelu_f(acc[mt][nt][3] + bn_);
                int pk = __builtin_amdgcn_cvt_pk_fp8_f32(v0, v1, 0, false);
                pk     = __builtin_amdgcn_cvt_pk_fp8_f32(v2, v3, pk, true);
                unsigned char* o = (unsigned char*)out + (size_t)m0 * N + n;
                o[0]             = (unsigned char)pk;
                o[(size_t)N]     = (unsigned char)(pk >> 8);
                o[(size_t)2 * N] = (unsigned char)(pk >> 16);
                o[(size_t)3 * N] = (unsigned char)(pk >> 24);
            } else {   // MODE 3
                #pragma unroll
                for (int r = 0; r < 4; ++r) {
                    int m = bm + wm + mt * 16 + quad * 4 + r;
                    int n = bn + wn + nt * 16 + cc;
                    float v = acc[mt][nt][r] + bias[n];
                    int b_ = m >> 11, srow = m & 2047;
                    int which = n >> 10, rem = n & 1023;
                    int h = rem >> 6, d = rem & 63;
                    if (which == 0) v *= 0.125f;   // fold 1/sqrt(HD) into Q
                    size_t idx = ((((size_t)which * BATCH + b_) * NH + h) * SEQ + srow) * HD + d;
                    ((unsigned short*)out)[idx] = f2bf(v);
                }
            }
        }
}

// ---------------- fp8 NT GEMM (FC2 split-K): 3-buffer depth-2 counted-vmcnt pipeline ----
__global__ __launch_bounds__(256) void gemm_fp8(
        const unsigned char* __restrict__ A,
        const unsigned char* __restrict__ Bw,
        unsigned short* __restrict__ p0, unsigned short* __restrict__ p1,
        unsigned short* __restrict__ p2, unsigned short* __restrict__ p3,
        int M, int N, int K, int KC) {
    __shared__ unsigned char As[3][128 * 64];   // 3 x 8 KB
    __shared__ unsigned char Bs[3][128 * 64];   // 3 x 8 KB

    const int tid  = threadIdx.x;
    const int wave = tid >> 6;
    const int lane = tid & 63;
    const int quad = lane >> 4;
    const int cc   = lane & 15;
    const int bn = blockIdx.x * 128;
    const int bm = blockIdx.y * 128;

    const unsigned char* Ab = A  + (size_t)bm * K;
    const unsigned char* Bb = Bw + (size_t)bn * K;

    const int srow0 = tid >> 2;
    const int schunk = tid & 3;
    const int rsw = (cc >> 1) & 3;
    const int wm = (wave >> 1) * 64;
    const int wn = (wave & 1) * 64;

    const int kbeg = blockIdx.z * KC;

    f32x4 acc[4][4] = {};

    auto stage = [&](int buf, int k0) {
        #pragma unroll
        for (int i = 0; i < 2; ++i) {
            int row = i * 64 + srow0;
            int g   = schunk ^ ((row >> 1) & 3);
            const unsigned char* ga = Ab + (size_t)row * K + k0 + g * 16;
            const unsigned char* gb = Bb + (size_t)row * K + k0 + g * 16;
            unsigned char* la = &As[buf][i * 4096 + wave * 1024];
            unsigned char* lb = &Bs[buf][i * 4096 + wave * 1024];
            __builtin_amdgcn_global_load_lds((gas_t)(const void*)ga, (las_t)(void*)la, 16, 0, 0);
            __builtin_amdgcn_global_load_lds((gas_t)(const void*)gb, (las_t)(void*)lb, 16, 0, 0);
        }
    };

    const int nkt = KC >> 6;   // 16 for KC=1024
    stage(0, kbeg);
    if (nkt > 1) {
        stage(1, kbeg + 64);
        asm volatile("s_waitcnt vmcnt(4)" ::: "memory");   // buf0 landed; buf1 in flight
    } else {
        asm volatile("s_waitcnt vmcnt(0)" ::: "memory");
    }
    __builtin_amdgcn_s_barrier();

    int cur = 0;
    for (int kt = 0; kt < nkt; ++kt) {
        int pbuf = cur + 2; if (pbuf >= 3) pbuf -= 3;      // (cur+2)%3
        if (kt + 2 < nkt) stage(pbuf, kbeg + ((kt + 2) << 6));

        long af[4][2], bf[4][2];
        #pragma unroll
        for (int mt = 0; mt < 4; ++mt)
            #pragma unroll
            for (int s = 0; s < 2; ++s) {
                int slot = ((quad >> 1) + 2 * s) ^ rsw;
                af[mt][s] = *(const long*)&As[cur][(wm + mt * 16 + cc) * 64 + slot * 16 + (quad & 1) * 8];
            }
        #pragma unroll
        for (int nt = 0; nt < 4; ++nt)
            #pragma unroll
            for (int s = 0; s < 2; ++s) {
                int slot = ((quad >> 1) + 2 * s) ^ rsw;
                bf[nt][s] = *(const long*)&Bs[cur][(wn + nt * 16 + cc) * 64 + slot * 16 + (quad & 1) * 8];
            }

        #pragma unroll
        for (int mt = 0; mt < 4; ++mt)
            #pragma unroll
            for (int nt = 0; nt < 4; ++nt) {
                acc[mt][nt] = __builtin_amdgcn_mfma_f32_16x16x32_fp8_fp8(
                    af[mt][0], bf[nt][0], acc[mt][nt], 0, 0, 0);
                acc[mt][nt] = __builtin_amdgcn_mfma_f32_16x16x32_fp8_fp8(
                    af[mt][1], bf[nt][1], acc[mt][nt], 0, 0, 0);
            }

        if (kt + 1 < nkt) {
            asm volatile("s_waitcnt lgkmcnt(0)" ::: "memory");   // my LDS reads done
            if (kt + 2 < nkt)
                asm volatile("s_waitcnt vmcnt(4)" ::: "memory"); // kt+1 landed; kt+2 in flight
            else
                asm volatile("s_waitcnt vmcnt(0)" ::: "memory"); // tail: drain final tile
            __builtin_amdgcn_s_barrier();
        }
        cur = (cur < 2) ? cur + 1 : 0;
    }

    unsigned short* outp = (blockIdx.z == 0) ? p0
                         : (blockIdx.z == 1) ? p1
                         : (blockIdx.z == 2) ? p2 : p3;
    #pragma unroll
    for (int mt = 0; mt < 4; ++mt)
        #pragma unroll
        for (int nt = 0; nt < 4; ++nt)
            #pragma unroll
            for (int r = 0; r < 4; ++r) {
                int m = bm + wm + mt * 16 + quad * 4 + r;
                int n = bn + wn + nt * 16 + cc;
                outp[(size_t)m * N + n] = f2bf(acc[mt][nt][r]);
            }
}

// ---------------- V transpose: [bh][s][hd] -> [bh][hd][s] ----------------
__global__ __launch_bounds__(256) void transpose_v(
        const unsigned short* __restrict__ vsrc, unsigned short* __restrict__ vt) {
    __shared__ unsigned short Ls[64 * 72];
    const int t = threadIdx.x;
    const int s0 = blockIdx.x * 64;
    const int bh = blockIdx.y;
    const unsigned short* in = vsrc + (size_t)bh * SEQ * HD;
    unsigned short* outp = vt + (size_t)bh * SEQ * HD;

    const int row = t >> 2;
    const int c8  = (t & 3) * 8;
    #pragma unroll
    for (int p = 0; p < 2; ++p)
        *(uint4*)&Ls[row * 72 + c8 + p * 32] =
            *(const uint4*)&in[(size_t)(s0 + row) * HD + c8 + p * 32];
    __syncthreads();

    const int hd = t >> 2;
    #pragma unroll
    for (int p = 0; p < 2; ++p) {
        unsigned short tmp[8];
        #pragma unroll
        for (int j = 0; j < 8; ++j)
            tmp[j] = Ls[(c8 + p * 32 + j) * 72 + hd];
        *(uint4*)&outp[(size_t)hd * SEQ + s0 + c8 + p * 32] = *(uint4*)tmp;
    }
}

// ---------------- MFMA flash attention v11: T14 + K/V XOR-swizzle (unchanged) ----------
#define KPAD 72
__global__ __launch_bounds__(256, 4) void attn_mfma(
        const unsigned short* __restrict__ qkv,
        const unsigned short* __restrict__ vt,
        float* __restrict__ op0, float* __restrict__ op1,
        float* __restrict__ lpart) {
    const int tid  = threadIdx.x;
    const int wave = tid >> 6;
    const int lane = tid & 63;
    const int quad = lane >> 4;
    const int cc   = lane & 15;
    const int qblk = blockIdx.x;
    const int bh   = blockIdx.y;
    const int half = blockIdx.z;

    const size_t headsz = (size_t)SEQ * HD;
    const unsigned short* qb  = qkv + (size_t)bh * headsz;
    const unsigned short* kb  = qkv + ((size_t)BATCH * NH + bh) * headsz;
    const unsigned short* vtb = vt + (size_t)bh * headsz;
    float* opart = half ? op1 : op0;
    float* lp    = lpart + (size_t)half * BATCH * NH * SEQ;

    __shared__ unsigned short Ks[64 * 64];       // 8 KB, swizzled
    __shared__ unsigned short Vt[64 * 64];       // 8 KB, swizzled
    __shared__ unsigned short Ps[4 * 32 * KPAD]; // 18 KB, v6 layout

    bf16x8 qa[2][2];
    #pragma unroll
    for (int mt = 0; mt < 2; ++mt) {
        const unsigned short* qp =
            qb + (size_t)(qblk * 128 + wave * 32 + mt * 16 + cc) * HD + quad * 8;
        qa[mt][0] = *(const bf16x8*)qp;
        qa[mt][1] = *(const bf16x8*)(qp + 32);
    }

    f32x4 o_acc[2][4] = {};
    float l_i[2][4] = {};

    // staging geometry: 8 lanes per row, rows srow0 and srow0+8
    const int srow0 = wave * 16 + (lane >> 3);
    const int sc8c  = lane & 7;                      // logical 16B chunk
    const int swz   = (sc8c ^ (lane >> 3)) * 8;      // phys chunk offset (row&7 == lane>>3)
    const int psw   = (cc >> 2) & 3;
    const int rw7   = cc & 7;                        // fragment row & 7 for reads

    const int kt0 = half * 16, ktend = kt0 + 16;

    // prologue prefetch: named scalars (rule #20 — no arrays, no conditional defs)
    uint4 ka0, ka1, va0, va1;
    {
        const unsigned short* kp0 = &kb[(size_t)(kt0 * 64 + srow0) * HD + sc8c * 8];
        const unsigned short* vp0 = &vtb[(size_t)srow0 * SEQ + kt0 * 64 + sc8c * 8];
        ka0 = *(const uint4*)kp0;
        ka1 = *(const uint4*)(kp0 + 8 * HD);     // row srow0+8
        va0 = *(const uint4*)vp0;
        va1 = *(const uint4*)(vp0 + 8 * SEQ);    // row srow0+8
    }

    for (int kt = kt0; kt < ktend; ++kt) {
        __syncthreads();   // prev readers done
        *(uint4*)&Ks[srow0 * 64 + swz]        = ka0;
        *(uint4*)&Ks[(srow0 + 8) * 64 + swz]  = ka1;
        *(uint4*)&Vt[srow0 * 64 + swz]        = va0;
        *(uint4*)&Vt[(srow0 + 8) * 64 + swz]  = va1;
        __syncthreads();   // tile visible

        // issue next-tile loads NOW (unconditional, clamped) — hide under compute
        int ktn = (kt + 1 < ktend) ? kt + 1 : kt;
        const unsigned short* kpn = &kb[(size_t)(ktn * 64 + srow0) * HD + sc8c * 8];
        const unsigned short* vpn = &vtb[(size_t)srow0 * SEQ + ktn * 64 + sc8c * 8];
        uint4 nk0 = *(const uint4*)kpn;
        uint4 nk1 = *(const uint4*)(kpn + 8 * HD);
        uint4 nv0 = *(const uint4*)vpn;
        uint4 nv1 = *(const uint4*)(vpn + 8 * SEQ);

        f32x4 s_acc[2][4];
        #pragma unroll
        for (int nt = 0; nt < 4; ++nt) {
            const unsigned short* kp = &Ks[(nt * 16 + cc) * 64];
            bf16x8 kf0 = *(const bf16x8*)&kp[(quad ^ rw7) * 8];
            bf16x8 kf1 = *(const bf16x8*)&kp[((quad + 4) ^ rw7) * 8];
            #pragma unroll
            for (int mt = 0; mt < 2; ++mt) {
                f32x4 z = {};
                z = __builtin_amdgcn_mfma_f32_16x16x32_bf16(qa[mt][0], kf0, z, 0, 0, 0);
                s_acc[mt][nt] = __builtin_amdgcn_mfma_f32_16x16x32_bf16(qa[mt][1], kf1, z, 0, 0, 0);
            }
        }

        unsigned short* pw = &Ps[wave * 32 * KPAD];
        #pragma unroll
        for (int mt = 0; mt < 2; ++mt)
            #pragma unroll
            for (int nt = 0; nt < 4; ++nt) {
                int pc = ((nt ^ quad) & 3) * 16 + cc;
                #pragma unroll
                for (int r = 0; r < 4; ++r) {
                    float e = __expf(s_acc[mt][nt][r]);
                    l_i[mt][r] += e;
                    pw[(mt * 16 + quad * 4 + r) * KPAD + pc] = f2bf_up(e);
                }
            }

        bf16x8 pf[2][2];
        #pragma unroll
        for (int mt = 0; mt < 2; ++mt) {
            const unsigned short* pa = &pw[(mt * 16 + cc) * KPAD];
            pf[mt][0] = *(const bf16x8*)&pa[((((quad >> 1))     ^ psw) & 3) * 16 + (quad & 1) * 8];
            pf[mt][1] = *(const bf16x8*)&pa[(((2 + (quad >> 1)) ^ psw) & 3) * 16 + (quad & 1) * 8];
        }

        #pragma unroll
        for (int nt = 0; nt < 4; ++nt) {
            const unsigned short* vp = &Vt[(nt * 16 + cc) * 64];
            bf16x8 vf0 = *(const bf16x8*)&vp[(quad ^ rw7) * 8];
            bf16x8 vf1 = *(const bf16x8*)&vp[((quad + 4) ^ rw7) * 8];
            #pragma unroll
            for (int mt = 0; mt < 2; ++mt) {
                o_acc[mt][nt] = __builtin_amdgcn_mfma_f32_16x16x32_bf16(
                    pf[mt][0], vf0, o_acc[mt][nt], 0, 0, 0);
                o_acc[mt][nt] = __builtin_amdgcn_mfma_f32_16x16x32_bf16(
                    pf[mt][1], vf1, o_acc[mt][nt], 0, 0, 0);
            }
        }

        ka0 = nk0; ka1 = nk1; va0 = nv0; va1 = nv1;   // register moves
    }

    #pragma unroll
    for (int mt = 0; mt < 2; ++mt) {
        float lr[4];
        #pragma unroll
        for (int r = 0; r < 4; ++r) {
            float l = l_i[mt][r];
            #pragma unroll
            for (int off = 1; off < 16; off <<= 1)
                l += __shfl_xor(l, off, 64);
            lr[r] = l;
        }
        int rowbase = qblk * 128 + wave * 32 + mt * 16;
        if (cc == 0) {
            float4 lv = {lr[0], lr[1], lr[2], lr[3]};
            *(float4*)&lp[(size_t)bh * SEQ + rowbase + quad * 4] = lv;
        }
        #pragma unroll
        for (int nt = 0; nt < 4; ++nt)
            #pragma unroll
            for (int r = 0; r < 4; ++r) {
                int row = rowbase + quad * 4 + r;
                opart[((size_t)bh * SEQ + row) * HD + nt * 16 + cc] = o_acc[mt][nt][r];
            }
    }
}

extern "C" void kernel_launch(void* const* d_in, const int* in_sizes, int n_in,
                              void* d_out, int out_size, void* d_ws, size_t ws_size,
                              hipStream_t stream) {
    const float* src       = (const float*)d_in[0];
    const float* pre_gamma = (const float*)d_in[1];
    const float* pre_beta  = (const float*)d_in[2];
    const float* qkv_w     = (const float*)d_in[3];
    const float* qkv_b     = (const float*)d_in[4];
    const float* an_gamma  = (const float*)d_in[5];
    const float* an_beta   = (const float*)d_in[6];
    const float* fc1_w     = (const float*)d_in[7];
    const float* fc1_b     = (const float*)d_in[8];
    const float* fc2_w     = (const float*)d_in[9];
    const float* fc2_b     = (const float*)d_in[10];
    float* out = (float*)d_out;

    char* ws = (char*)d_ws;
    size_t off = 0;
    auto alloc = [&](size_t bytes) {
        char* p = ws + off;
        off += (bytes + 255) & ~(size_t)255;
        return p;
    };
    float*          x_f   = (float*)alloc((size_t)MROWS * DMODEL * 4);
    unsigned short* x_b   = (unsigned short*)alloc((size_t)MROWS * DMODEL * 2);
    float*          y_f   = (float*)alloc((size_t)MROWS * DMODEL * 4);
    unsigned short* y_b   = (unsigned short*)alloc((size_t)MROWS * DMODEL * 2);
    float*          atf   = (float*)alloc((size_t)MROWS * DMODEL * 4);
    float*          fff   = (float*)alloc((size_t)MROWS * DMODEL * 4);
    unsigned short* qkvb  = (unsigned short*)alloc((size_t)3 * MROWS * DMODEL * 2);
    unsigned char*  h8    = (unsigned char*)alloc((size_t)MROWS * FFN_DIM * 2);
    unsigned short* wqkv  = (unsigned short*)alloc((size_t)3 * DMODEL * DMODEL * 2);
    unsigned short* wfc1  = (unsigned short*)alloc((size_t)FFN_DIM * DMODEL * 2);
    unsigned char*  wfc28 = (unsigned char*)alloc((size_t)DMODEL * FFN_DIM);

    unsigned short* vt_b = (unsigned short*)fff;
    float* opart0 = atf;
    float* opart1 = (float*)h8;
    float* lpart  = (float*)x_b;
    unsigned short* fc2p0 = (unsigned short*)fff;
    unsigned short* fc2p1 = (unsigned short*)x_f;
    unsigned short* fc2p2 = (unsigned short*)atf;
    unsigned short* fc2p3 = (unsigned short*)qkvb;

    int n_qkv4 = 3 * DMODEL * DMODEL / 4;
    int n_fc4  = FFN_DIM * DMODEL / 4;
    int cvt_blocks = (n_qkv4 + 2 * n_fc4 + 255) / 256;

    // fused pre-LN + weight conversion (one dispatch; phases overlap)
    ln_pre_cvt<<<dim3(MROWS + cvt_blocks), dim3(256), 0, stream>>>(
        src, pre_gamma, pre_beta, x_f, x_b,
        qkv_w, wqkv, n_qkv4, fc1_w, wfc1, n_fc4, fc2_w, wfc28, n_fc4);

    gemm_lds<3><<<dim3(3 * DMODEL / 128, MROWS / 128), dim3(256), 0, stream>>>(
        x_b, wqkv, qkv_b, qkvb, MROWS, 3 * DMODEL, DMODEL);
    transpose_v<<<dim3(SEQ / 64, BATCH * NH), dim3(256), 0, stream>>>(
        qkvb + (size_t)2 * BATCH * NH * SEQ * HD, vt_b);
    attn_mfma<<<dim3(SEQ / 128, BATCH * NH, 2), dim3(256), 0, stream>>>(
        qkvb, vt_b, opart0, opart1, lpart);
    ln_attn<<<dim3(MROWS), dim3(256), 0, stream>>>(
        opart0, opart1, lpart, lpart + (size_t)BATCH * NH * SEQ,
        x_f, an_gamma, an_beta, y_f, y_b);
    gemm_lds<1><<<dim3(FFN_DIM / 128, MROWS / 128), dim3(256), 0, stream>>>(
        y_b, wfc1, fc1_b, h8, MROWS, FFN_DIM, DMODEL);
    gemm_fp8<<<dim3(DMODEL / 128, MROWS / 128, 4), dim3(256), 0, stream>>>(
        h8, wfc28, fc2p0, fc2p1, fc2p2, fc2p3, MROWS, DMODEL, FFN_DIM, 1024);
    ln_fc2<<<dim3(MROWS), dim3(256), 0, stream>>>(
        fc2p0, fc2p1, fc2p2, fc2p3, fc2_b, y_f, an_gamma, an_beta, out);
}

// Round 9
// 315.474 us; speedup vs baseline: 1.0354x; 1.0354x over previous
//
#include <hip/hip_runtime.h>
#include <hip/hip_bf16.h>
#include <math.h>

#define DMODEL 1024
#define NH 16
#define HD 64
#define SEQ 2048
#define BATCH 2
#define MROWS (BATCH * SEQ)   // 4096
#define FFN_DIM 4096

using bf16x8 = __attribute__((ext_vector_type(8))) __bf16;
using f32x4  = __attribute__((ext_vector_type(4))) float;

typedef const __attribute__((address_space(1))) unsigned char* gas_t;
typedef __attribute__((address_space(3))) unsigned char* las_t;

__device__ inline unsigned short f2bf(float f) {
    unsigned int u = __builtin_bit_cast(unsigned int, f);
    u += 0x7fffu + ((u >> 16) & 1u);   // round-to-nearest-even
    return (unsigned short)(u >> 16);
}
__device__ inline unsigned short f2bf_up(float f) {
    unsigned int u = __builtin_bit_cast(unsigned int, f);
    return (unsigned short)((u + 0x8000u) >> 16);
}
__device__ inline float bf2f(unsigned short u) {
    unsigned int v = ((unsigned int)u) << 16;
    return __builtin_bit_cast(float, v);
}
// tanh-GELU (branch-free): x * sigmoid(1.59577x + 0.0713548x^3); |err| <= ~3e-3
__device__ inline float gelu_f(float x) {
    float x2 = x * x;
    float w = x * fmaf(0.07135481627f, x2, 1.59576912161f);
    return x / (1.0f + __expf(-w));
}

// ---------------- fused: pre-LayerNorm (blocks < MROWS) + weight cvt (rest) ----------------
// qkv/fc1 weights -> bf16; fc2 weights -> fp8 via HW packed cvt
__global__ __launch_bounds__(256) void ln_pre_cvt(
        const float* __restrict__ a,
        const float* __restrict__ gamma, const float* __restrict__ beta,
        float* __restrict__ out_f, unsigned short* __restrict__ out_b,
        const float* __restrict__ wa, unsigned short* __restrict__ oa, int na4,
        const float* __restrict__ wb, unsigned short* __restrict__ ob, int nb4,
        const float* __restrict__ wc, unsigned char* __restrict__ oc, int nc4) {
    int blk = blockIdx.x;
    int t = threadIdx.x;
    if (blk >= MROWS) {
        int i = (blk - MROWS) * 256 + t;
        if (i < na4) {
            float4 v = ((const float4*)wa)[i];
            ushort4 o;
            o.x = f2bf(v.x); o.y = f2bf(v.y); o.z = f2bf(v.z); o.w = f2bf(v.w);
            ((ushort4*)oa)[i] = o;
        } else if (i < na4 + nb4) {
            int j = i - na4;
            float4 v = ((const float4*)wb)[j];
            ushort4 o;
            o.x = f2bf(v.x); o.y = f2bf(v.y); o.z = f2bf(v.z); o.w = f2bf(v.w);
            ((ushort4*)ob)[j] = o;
        } else if (i < na4 + nb4 + nc4) {
            int j = i - na4 - nb4;
            float4 v = ((const float4*)wc)[j];
            int pk = __builtin_amdgcn_cvt_pk_fp8_f32(v.x, v.y, 0, false);
            pk     = __builtin_amdgcn_cvt_pk_fp8_f32(v.z, v.w, pk, true);
            ((unsigned int*)oc)[j] = (unsigned int)pk;
        }
        return;
    }
    int row = blk;
    float4 v = ((const float4*)(a + (size_t)row * DMODEL))[t];
    float s  = v.x + v.y + v.z + v.w;
    float s2 = v.x * v.x + v.y * v.y + v.z * v.z + v.w * v.w;
    #pragma unroll
    for (int off = 32; off > 0; off >>= 1) {
        s  += __shfl_xor(s,  off, 64);
        s2 += __shfl_xor(s2, off, 64);
    }
    __shared__ float red[8];
    int wave = t >> 6, lane = t & 63;
    if (lane == 0) { red[wave] = s; red[4 + wave] = s2; }
    __syncthreads();
    float tot  = red[0] + red[1] + red[2] + red[3];
    float tot2 = red[4] + red[5] + red[6] + red[7];
    float mu   = tot * (1.0f / DMODEL);
    float var  = tot2 * (1.0f / DMODEL) - mu * mu;
    float rstd = rsqrtf(var + 1e-5f);
    float4 g  = ((const float4*)gamma)[t];
    float4 be = ((const float4*)beta)[t];
    float4 o;
    o.x = (v.x - mu) * rstd * g.x + be.x;
    o.y = (v.y - mu) * rstd * g.y + be.y;
    o.z = (v.z - mu) * rstd * g.z + be.z;
    o.w = (v.w - mu) * rstd * g.w + be.w;
    ((float4*)(out_f + (size_t)row * DMODEL))[t] = o;
    ushort4 ob4;
    ob4.x = f2bf(o.x); ob4.y = f2bf(o.y); ob4.z = f2bf(o.z); ob4.w = f2bf(o.w);
    ((ushort4*)(out_b + (size_t)row * DMODEL))[t] = ob4;
}

// ---------------- AddNorm1 fused with attention combine ----------------
__global__ __launch_bounds__(256) void ln_attn(
        const float* __restrict__ o0, const float* __restrict__ o1,
        const float* __restrict__ l0, const float* __restrict__ l1,
        const float* __restrict__ xres,
        const float* __restrict__ gamma, const float* __restrict__ beta,
        float* __restrict__ out_f, unsigned short* __restrict__ out_b) {
    int row = blockIdx.x;
    int t = threadIdx.x;
    int b_ = row >> 11, s = row & 2047;
    int h = t >> 4;
    int bh = b_ * NH + h;
    size_t obase = ((size_t)bh * SEQ + s) * HD + (4 * t & 63);
    float4 va = ((const float4*)(o0 + obase))[0];
    float4 vb = ((const float4*)(o1 + obase))[0];
    float inv_l = 1.0f / (l0[(size_t)bh * SEQ + s] + l1[(size_t)bh * SEQ + s]);
    float4 rr = ((const float4*)(xres + (size_t)row * DMODEL))[t];
    float4 v;
    v.x = (va.x + vb.x) * inv_l + rr.x;
    v.y = (va.y + vb.y) * inv_l + rr.y;
    v.z = (va.z + vb.z) * inv_l + rr.z;
    v.w = (va.w + vb.w) * inv_l + rr.w;

    float s1 = v.x + v.y + v.z + v.w;
    float s2 = v.x * v.x + v.y * v.y + v.z * v.z + v.w * v.w;
    #pragma unroll
    for (int off = 32; off > 0; off >>= 1) {
        s1 += __shfl_xor(s1, off, 64);
        s2 += __shfl_xor(s2, off, 64);
    }
    __shared__ float red[8];
    int wave = t >> 6, lane = t & 63;
    if (lane == 0) { red[wave] = s1; red[4 + wave] = s2; }
    __syncthreads();
    float tot  = red[0] + red[1] + red[2] + red[3];
    float tot2 = red[4] + red[5] + red[6] + red[7];
    float mu   = tot * (1.0f / DMODEL);
    float var  = tot2 * (1.0f / DMODEL) - mu * mu;
    float rstd = rsqrtf(var + 1e-5f);
    float4 g  = ((const float4*)gamma)[t];
    float4 be = ((const float4*)beta)[t];
    float4 o;
    o.x = (v.x - mu) * rstd * g.x + be.x;
    o.y = (v.y - mu) * rstd * g.y + be.y;
    o.z = (v.z - mu) * rstd * g.z + be.z;
    o.w = (v.w - mu) * rstd * g.w + be.w;
    ((float4*)(out_f + (size_t)row * DMODEL))[t] = o;
    ushort4 ob;
    ob.x = f2bf(o.x); ob.y = f2bf(o.y); ob.z = f2bf(o.z); ob.w = f2bf(o.w);
    ((ushort4*)(out_b + (size_t)row * DMODEL))[t] = ob;
}

// ---------------- AddNorm fused with split-K=2 reduction (FC2 epilogue) ----------------
__global__ __launch_bounds__(256) void ln_fc2(
        const unsigned short* __restrict__ p0, const unsigned short* __restrict__ p1,
        const float* __restrict__ bias, const float* __restrict__ resid,
        const float* __restrict__ gamma, const float* __restrict__ beta,
        float* __restrict__ out_f) {
    int row = blockIdx.x;
    int t = threadIdx.x;
    size_t base = (size_t)row * DMODEL;
    ushort4 u0 = ((const ushort4*)(p0 + base))[t];
    ushort4 u1 = ((const ushort4*)(p1 + base))[t];
    float4 bb = ((const float4*)bias)[t];
    float4 rr = ((const float4*)(resid + base))[t];
    float4 v;
    v.x = bf2f(u0.x) + bf2f(u1.x) + bb.x + rr.x;
    v.y = bf2f(u0.y) + bf2f(u1.y) + bb.y + rr.y;
    v.z = bf2f(u0.z) + bf2f(u1.z) + bb.z + rr.z;
    v.w = bf2f(u0.w) + bf2f(u1.w) + bb.w + rr.w;

    float s  = v.x + v.y + v.z + v.w;
    float s2 = v.x * v.x + v.y * v.y + v.z * v.z + v.w * v.w;
    #pragma unroll
    for (int off = 32; off > 0; off >>= 1) {
        s  += __shfl_xor(s,  off, 64);
        s2 += __shfl_xor(s2, off, 64);
    }
    __shared__ float red[8];
    int wave = t >> 6, lane = t & 63;
    if (lane == 0) { red[wave] = s; red[4 + wave] = s2; }
    __syncthreads();
    float tot  = red[0] + red[1] + red[2] + red[3];
    float tot2 = red[4] + red[5] + red[6] + red[7];
    float mu   = tot * (1.0f / DMODEL);
    float var  = tot2 * (1.0f / DMODEL) - mu * mu;
    float rstd = rsqrtf(var + 1e-5f);
    float4 g  = ((const float4*)gamma)[t];
    float4 be = ((const float4*)beta)[t];
    float4 o;
    o.x = (v.x - mu) * rstd * g.x + be.x;
    o.y = (v.y - mu) * rstd * g.y + be.y;
    o.z = (v.z - mu) * rstd * g.z + be.z;
    o.w = (v.w - mu) * rstd * g.w + be.w;
    ((float4*)(out_f + base))[t] = o;
}

// ---------------- LDS-staged bf16 NT GEMM, BK=64, double-buffered 2-phase ----------------
// (reverted to the proven 318.1us version — BK=32 3-buffer port cost ~8us net)
// MODE 1: bias+GELU(tanh) -> fp8 out.  MODE 3: qkv scatter bf16 (q pre-scaled).
template <int MODE>
__global__ __launch_bounds__(256) void gemm_lds(
        const unsigned short* __restrict__ A,
        const unsigned short* __restrict__ Bw,
        const float* __restrict__ bias,
        void* __restrict__ out, int M, int N, int K) {
    __shared__ unsigned short As[2][128 * 64];   // 2 x 16 KB
    __shared__ unsigned short Bs[2][128 * 64];   // 2 x 16 KB

    const int tid  = threadIdx.x;
    const int wave = tid >> 6;
    const int lane = tid & 63;
    const int quad = lane >> 4;
    const int cc   = lane & 15;
    const int bn = blockIdx.x * 128;
    const int bm = blockIdx.y * 128;

    const unsigned short* Ab = A  + (size_t)bm * K;
    const unsigned short* Bb = Bw + (size_t)bn * K;

    const int srow0 = tid >> 3;
    const int sslot = tid & 7;
    const int rsw   = (cc >> 1) & 7;
    const int wm = (wave >> 1) * 64;
    const int wn = (wave & 1) * 64;

    f32x4 acc[4][4] = {};

    auto stage = [&](int buf, int k0) {
        #pragma unroll
        for (int i = 0; i < 4; ++i) {
            int row = i * 32 + srow0;
            int g   = sslot ^ ((row >> 1) & 7);
            const unsigned short* ga = Ab + (size_t)row * K + k0 + g * 8;
            const unsigned short* gb = Bb + (size_t)row * K + k0 + g * 8;
            unsigned short* la = &As[buf][i * 2048 + wave * 512];
            unsigned short* lb = &Bs[buf][i * 2048 + wave * 512];
            __builtin_amdgcn_global_load_lds((gas_t)(const void*)ga, (las_t)(void*)la, 16, 0, 0);
            __builtin_amdgcn_global_load_lds((gas_t)(const void*)gb, (las_t)(void*)lb, 16, 0, 0);
        }
    };

    const int nkt = K >> 6;
    stage(0, 0);
    __syncthreads();          // drains vmcnt(0): buf0 ready

    int cur = 0;
    for (int kt = 0; kt < nkt; ++kt) {
        if (kt + 1 < nkt) stage(cur ^ 1, (kt + 1) << 6);   // prefetch overlaps compute

        bf16x8 af[4][2], bf[4][2];
        #pragma unroll
        for (int mt = 0; mt < 4; ++mt)
            #pragma unroll
            for (int s = 0; s < 2; ++s) {
                int slot = (s * 4 + quad) ^ rsw;
                af[mt][s] = *(const bf16x8*)&As[cur][(wm + mt * 16 + cc) * 64 + slot * 8];
            }
        #pragma unroll
        for (int nt = 0; nt < 4; ++nt)
            #pragma unroll
            for (int s = 0; s < 2; ++s) {
                int slot = (s * 4 + quad) ^ rsw;
                bf[nt][s] = *(const bf16x8*)&Bs[cur][(wn + nt * 16 + cc) * 64 + slot * 8];
            }

        #pragma unroll
        for (int mt = 0; mt < 4; ++mt)
            #pragma unroll
            for (int nt = 0; nt < 4; ++nt) {
                acc[mt][nt] = __builtin_amdgcn_mfma_f32_16x16x32_bf16(
                    af[mt][0], bf[nt][0], acc[mt][nt], 0, 0, 0);
                acc[mt][nt] = __builtin_amdgcn_mfma_f32_16x16x32_bf16(
                    af[mt][1], bf[nt][1], acc[mt][nt], 0, 0, 0);
            }

        if (kt + 1 < nkt) __syncthreads();
        cur ^= 1;
    }

    #pragma unroll
    for (int mt = 0; mt < 4; ++mt)
        #pragma unroll
        for (int nt = 0; nt < 4; ++nt) {
            if constexpr (MODE == 1) {
                int m0 = bm + wm + mt * 16 + quad * 4;
                int n  = bn + wn + nt * 16 + cc;
                float bn_ = bias[n];
                float v0 = gelu_f(acc[mt][nt][0] + bn_);
                float v1 = gelu_f(acc[mt][nt][1] + bn_);
                float v2 = gelu_f(acc[mt][nt][2] + bn_);
                float v3 = gelu_f(acc[mt][nt][3] + bn_);
                int pk = __builtin_amdgcn_cvt_pk_fp8_f32(v0, v1, 0, false);
                pk     = __builtin_amdgcn_cvt_pk_fp8_f32(v2, v3, pk, true);
                unsigned char* o = (unsigned char*)out + (size_t)m0 * N + n;
                o[0]             = (unsigned char)pk;
                o[(size_t)N]     = (unsigned char)(pk >> 8);
                o[(size_t)2 * N] = (unsigned char)(pk >> 16);
                o[(size_t)3 * N] = (unsigned char)(pk >> 24);
            } else {   // MODE 3
                #pragma unroll
                for (int r = 0; r < 4; ++r) {
                    int m = bm + wm + mt * 16 + quad * 4 + r;
                    int n = bn + wn + nt * 16 + cc;
                    float v = acc[mt][nt][r] + bias[n];
                    int b_ = m >> 11, srow = m & 2047;
                    int which = n >> 10, rem = n & 1023;
                    int h = rem >> 6, d = rem & 63;
                    if (which == 0) v *= 0.125f;   // fold 1/sqrt(HD) into Q
                    size_t idx = ((((size_t)which * BATCH + b_) * NH + h) * SEQ + srow) * HD + d;
                    ((unsigned short*)out)[idx] = f2bf(v);
                }
            }
        }
}

// ---------------- fp8 NT GEMM (FC2 split-K=2): 3-buffer depth-2 counted-vmcnt pipeline ----
// validated skeleton (round 6); split-K halved 4->2: KC=2048, half the partial traffic,
// 2x K-steps per block for better pipeline amortization.
__global__ __launch_bounds__(256) void gemm_fp8(
        const unsigned char* __restrict__ A,
        const unsigned char* __restrict__ Bw,
        unsigned short* __restrict__ p0, unsigned short* __restrict__ p1,
        int M, int N, int K, int KC) {
    __shared__ unsigned char As[3][128 * 64];   // 3 x 8 KB
    __shared__ unsigned char Bs[3][128 * 64];   // 3 x 8 KB

    const int tid  = threadIdx.x;
    const int wave = tid >> 6;
    const int lane = tid & 63;
    const int quad = lane >> 4;
    const int cc   = lane & 15;
    const int bn = blockIdx.x * 128;
    const int bm = blockIdx.y * 128;

    const unsigned char* Ab = A  + (size_t)bm * K;
    const unsigned char* Bb = Bw + (size_t)bn * K;

    const int srow0 = tid >> 2;
    const int schunk = tid & 3;
    const int rsw = (cc >> 1) & 3;
    const int wm = (wave >> 1) * 64;
    const int wn = (wave & 1) * 64;

    const int kbeg = blockIdx.z * KC;

    f32x4 acc[4][4] = {};

    auto stage = [&](int buf, int k0) {
        #pragma unroll
        for (int i = 0; i < 2; ++i) {
            int row = i * 64 + srow0;
            int g   = schunk ^ ((row >> 1) & 3);
            const unsigned char* ga = Ab + (size_t)row * K + k0 + g * 16;
            const unsigned char* gb = Bb + (size_t)row * K + k0 + g * 16;
            unsigned char* la = &As[buf][i * 4096 + wave * 1024];
            unsigned char* lb = &Bs[buf][i * 4096 + wave * 1024];
            __builtin_amdgcn_global_load_lds((gas_t)(const void*)ga, (las_t)(void*)la, 16, 0, 0);
            __builtin_amdgcn_global_load_lds((gas_t)(const void*)gb, (las_t)(void*)lb, 16, 0, 0);
        }
    };

    const int nkt = KC >> 6;   // 32 for KC=2048
    stage(0, kbeg);
    if (nkt > 1) {
        stage(1, kbeg + 64);
        asm volatile("s_waitcnt vmcnt(4)" ::: "memory");   // buf0 landed; buf1 in flight
    } else {
        asm volatile("s_waitcnt vmcnt(0)" ::: "memory");
    }
    __builtin_amdgcn_s_barrier();

    int cur = 0;
    for (int kt = 0; kt < nkt; ++kt) {
        int pbuf = cur + 2; if (pbuf >= 3) pbuf -= 3;      // (cur+2)%3
        if (kt + 2 < nkt) stage(pbuf, kbeg + ((kt + 2) << 6));

        long af[4][2], bf[4][2];
        #pragma unroll
        for (int mt = 0; mt < 4; ++mt)
            #pragma unroll
            for (int s = 0; s < 2; ++s) {
                int slot = ((quad >> 1) + 2 * s) ^ rsw;
                af[mt][s] = *(const long*)&As[cur][(wm + mt * 16 + cc) * 64 + slot * 16 + (quad & 1) * 8];
            }
        #pragma unroll
        for (int nt = 0; nt < 4; ++nt)
            #pragma unroll
            for (int s = 0; s < 2; ++s) {
                int slot = ((quad >> 1) + 2 * s) ^ rsw;
                bf[nt][s] = *(const long*)&Bs[cur][(wn + nt * 16 + cc) * 64 + slot * 16 + (quad & 1) * 8];
            }

        #pragma unroll
        for (int mt = 0; mt < 4; ++mt)
            #pragma unroll
            for (int nt = 0; nt < 4; ++nt) {
                acc[mt][nt] = __builtin_amdgcn_mfma_f32_16x16x32_fp8_fp8(
                    af[mt][0], bf[nt][0], acc[mt][nt], 0, 0, 0);
                acc[mt][nt] = __builtin_amdgcn_mfma_f32_16x16x32_fp8_fp8(
                    af[mt][1], bf[nt][1], acc[mt][nt], 0, 0, 0);
            }

        if (kt + 1 < nkt) {
            asm volatile("s_waitcnt lgkmcnt(0)" ::: "memory");   // my LDS reads done
            if (kt + 2 < nkt)
                asm volatile("s_waitcnt vmcnt(4)" ::: "memory"); // kt+1 landed; kt+2 in flight
            else
                asm volatile("s_waitcnt vmcnt(0)" ::: "memory"); // tail: drain final tile
            __builtin_amdgcn_s_barrier();
        }
        cur = (cur < 2) ? cur + 1 : 0;
    }

    unsigned short* outp = (blockIdx.z == 0) ? p0 : p1;
    #pragma unroll
    for (int mt = 0; mt < 4; ++mt)
        #pragma unroll
        for (int nt = 0; nt < 4; ++nt)
            #pragma unroll
            for (int r = 0; r < 4; ++r) {
                int m = bm + wm + mt * 16 + quad * 4 + r;
                int n = bn + wn + nt * 16 + cc;
                outp[(size_t)m * N + n] = f2bf(acc[mt][nt][r]);
            }
}

// ---------------- V transpose: [bh][s][hd] -> [bh][hd][s] ----------------
__global__ __launch_bounds__(256) void transpose_v(
        const unsigned short* __restrict__ vsrc, unsigned short* __restrict__ vt) {
    __shared__ unsigned short Ls[64 * 72];
    const int t = threadIdx.x;
    const int s0 = blockIdx.x * 64;
    const int bh = blockIdx.y;
    const unsigned short* in = vsrc + (size_t)bh * SEQ * HD;
    unsigned short* outp = vt + (size_t)bh * SEQ * HD;

    const int row = t >> 2;
    const int c8  = (t & 3) * 8;
    #pragma unroll
    for (int p = 0; p < 2; ++p)
        *(uint4*)&Ls[row * 72 + c8 + p * 32] =
            *(const uint4*)&in[(size_t)(s0 + row) * HD + c8 + p * 32];
    __syncthreads();

    const int hd = t >> 2;
    #pragma unroll
    for (int p = 0; p < 2; ++p) {
        unsigned short tmp[8];
        #pragma unroll
        for (int j = 0; j < 8; ++j)
            tmp[j] = Ls[(c8 + p * 32 + j) * 72 + hd];
        *(uint4*)&outp[(size_t)hd * SEQ + s0 + c8 + p * 32] = *(uint4*)tmp;
    }
}

// ---------------- MFMA flash attention v11: T14 + K/V XOR-swizzle (unchanged) ----------
#define KPAD 72
__global__ __launch_bounds__(256, 4) void attn_mfma(
        const unsigned short* __restrict__ qkv,
        const unsigned short* __restrict__ vt,
        float* __restrict__ op0, float* __restrict__ op1,
        float* __restrict__ lpart) {
    const int tid  = threadIdx.x;
    const int wave = tid >> 6;
    const int lane = tid & 63;
    const int quad = lane >> 4;
    const int cc   = lane & 15;
    const int qblk = blockIdx.x;
    const int bh   = blockIdx.y;
    const int half = blockIdx.z;

    const size_t headsz = (size_t)SEQ * HD;
    const unsigned short* qb  = qkv + (size_t)bh * headsz;
    const unsigned short* kb  = qkv + ((size_t)BATCH * NH + bh) * headsz;
    const unsigned short* vtb = vt + (size_t)bh * headsz;
    float* opart = half ? op1 : op0;
    float* lp    = lpart + (size_t)half * BATCH * NH * SEQ;

    __shared__ unsigned short Ks[64 * 64];       // 8 KB, swizzled
    __shared__ unsigned short Vt[64 * 64];       // 8 KB, swizzled
    __shared__ unsigned short Ps[4 * 32 * KPAD]; // 18 KB, v6 layout

    bf16x8 qa[2][2];
    #pragma unroll
    for (int mt = 0; mt < 2; ++mt) {
        const unsigned short* qp =
            qb + (size_t)(qblk * 128 + wave * 32 + mt * 16 + cc) * HD + quad * 8;
        qa[mt][0] = *(const bf16x8*)qp;
        qa[mt][1] = *(const bf16x8*)(qp + 32);
    }

    f32x4 o_acc[2][4] = {};
    float l_i[2][4] = {};

    // staging geometry: 8 lanes per row, rows srow0 and srow0+8
    const int srow0 = wave * 16 + (lane >> 3);
    const int sc8c  = lane & 7;                      // logical 16B chunk
    const int swz   = (sc8c ^ (lane >> 3)) * 8;      // phys chunk offset (row&7 == lane>>3)
    const int psw   = (cc >> 2) & 3;
    const int rw7   = cc & 7;                        // fragment row & 7 for reads

    const int kt0 = half * 16, ktend = kt0 + 16;

    // prologue prefetch: named scalars (rule #20 — no arrays, no conditional defs)
    uint4 ka0, ka1, va0, va1;
    {
        const unsigned short* kp0 = &kb[(size_t)(kt0 * 64 + srow0) * HD + sc8c * 8];
        const unsigned short* vp0 = &vtb[(size_t)srow0 * SEQ + kt0 * 64 + sc8c * 8];
        ka0 = *(const uint4*)kp0;
        ka1 = *(const uint4*)(kp0 + 8 * HD);     // row srow0+8
        va0 = *(const uint4*)vp0;
        va1 = *(const uint4*)(vp0 + 8 * SEQ);    // row srow0+8
    }

    for (int kt = kt0; kt < ktend; ++kt) {
        __syncthreads();   // prev readers done
        *(uint4*)&Ks[srow0 * 64 + swz]        = ka0;
        *(uint4*)&Ks[(srow0 + 8) * 64 + swz]  = ka1;
        *(uint4*)&Vt[srow0 * 64 + swz]        = va0;
        *(uint4*)&Vt[(srow0 + 8) * 64 + swz]  = va1;
        __syncthreads();   // tile visible

        // issue next-tile loads NOW (unconditional, clamped) — hide under compute
        int ktn = (kt + 1 < ktend) ? kt + 1 : kt;
        const unsigned short* kpn = &kb[(size_t)(ktn * 64 + srow0) * HD + sc8c * 8];
        const unsigned short* vpn = &vtb[(size_t)srow0 * SEQ + ktn * 64 + sc8c * 8];
        uint4 nk0 = *(const uint4*)kpn;
        uint4 nk1 = *(const uint4*)(kpn + 8 * HD);
        uint4 nv0 = *(const uint4*)vpn;
        uint4 nv1 = *(const uint4*)(vpn + 8 * SEQ);

        f32x4 s_acc[2][4];
        #pragma unroll
        for (int nt = 0; nt < 4; ++nt) {
            const unsigned short* kp = &Ks[(nt * 16 + cc) * 64];
            bf16x8 kf0 = *(const bf16x8*)&kp[(quad ^ rw7) * 8];
            bf16x8 kf1 = *(const bf16x8*)&kp[((quad + 4) ^ rw7) * 8];
            #pragma unroll
            for (int mt = 0; mt < 2; ++mt) {
                f32x4 z = {};
                z = __builtin_amdgcn_mfma_f32_16x16x32_bf16(qa[mt][0], kf0, z, 0, 0, 0);
                s_acc[mt][nt] = __builtin_amdgcn_mfma_f32_16x16x32_bf16(qa[mt][1], kf1, z, 0, 0, 0);
            }
        }

        unsigned short* pw = &Ps[wave * 32 * KPAD];
        #pragma unroll
        for (int mt = 0; mt < 2; ++mt)
            #pragma unroll
            for (int nt = 0; nt < 4; ++nt) {
                int pc = ((nt ^ quad) & 3) * 16 + cc;
                #pragma unroll
                for (int r = 0; r < 4; ++r) {
                    float e = __expf(s_acc[mt][nt][r]);
                    l_i[mt][r] += e;
                    pw[(mt * 16 + quad * 4 + r) * KPAD + pc] = f2bf_up(e);
                }
            }

        bf16x8 pf[2][2];
        #pragma unroll
        for (int mt = 0; mt < 2; ++mt) {
            const unsigned short* pa = &pw[(mt * 16 + cc) * KPAD];
            pf[mt][0] = *(const bf16x8*)&pa[((((quad >> 1))     ^ psw) & 3) * 16 + (quad & 1) * 8];
            pf[mt][1] = *(const bf16x8*)&pa[(((2 + (quad >> 1)) ^ psw) & 3) * 16 + (quad & 1) * 8];
        }

        #pragma unroll
        for (int nt = 0; nt < 4; ++nt) {
            const unsigned short* vp = &Vt[(nt * 16 + cc) * 64];
            bf16x8 vf0 = *(const bf16x8*)&vp[(quad ^ rw7) * 8];
            bf16x8 vf1 = *(const bf16x8*)&vp[((quad + 4) ^ rw7) * 8];
            #pragma unroll
            for (int mt = 0; mt < 2; ++mt) {
                o_acc[mt][nt] = __builtin_amdgcn_mfma_f32_16x16x32_bf16(
                    pf[mt][0], vf0, o_acc[mt][nt], 0, 0, 0);
                o_acc[mt][nt] = __builtin_amdgcn_mfma_f32_16x16x32_bf16(
                    pf[mt][1], vf1, o_acc[mt][nt], 0, 0, 0);
            }
        }

        ka0 = nk0; ka1 = nk1; va0 = nv0; va1 = nv1;   // register moves
    }

    #pragma unroll
    for (int mt = 0; mt < 2; ++mt) {
        float lr[4];
        #pragma unroll
        for (int r = 0; r < 4; ++r) {
            float l = l_i[mt][r];
            #pragma unroll
            for (int off = 1; off < 16; off <<= 1)
                l += __shfl_xor(l, off, 64);
            lr[r] = l;
        }
        int rowbase = qblk * 128 + wave * 32 + mt * 16;
        if (cc == 0) {
            float4 lv = {lr[0], lr[1], lr[2], lr[3]};
            *(float4*)&lp[(size_t)bh * SEQ + rowbase + quad * 4] = lv;
        }
        #pragma unroll
        for (int nt = 0; nt < 4; ++nt)
            #pragma unroll
            for (int r = 0; r < 4; ++r) {
                int row = rowbase + quad * 4 + r;
                opart[((size_t)bh * SEQ + row) * HD + nt * 16 + cc] = o_acc[mt][nt][r];
            }
    }
}

extern "C" void kernel_launch(void* const* d_in, const int* in_sizes, int n_in,
                              void* d_out, int out_size, void* d_ws, size_t ws_size,
                              hipStream_t stream) {
    const float* src       = (const float*)d_in[0];
    const float* pre_gamma = (const float*)d_in[1];
    const float* pre_beta  = (const float*)d_in[2];
    const float* qkv_w     = (const float*)d_in[3];
    const float* qkv_b     = (const float*)d_in[4];
    const float* an_gamma  = (const float*)d_in[5];
    const float* an_beta   = (const float*)d_in[6];
    const float* fc1_w     = (const float*)d_in[7];
    const float* fc1_b     = (const float*)d_in[8];
    const float* fc2_w     = (const float*)d_in[9];
    const float* fc2_b     = (const float*)d_in[10];
    float* out = (float*)d_out;

    char* ws = (char*)d_ws;
    size_t off = 0;
    auto alloc = [&](size_t bytes) {
        char* p = ws + off;
        off += (bytes + 255) & ~(size_t)255;
        return p;
    };
    float*          x_f   = (float*)alloc((size_t)MROWS * DMODEL * 4);
    unsigned short* x_b   = (unsigned short*)alloc((size_t)MROWS * DMODEL * 2);
    float*          y_f   = (float*)alloc((size_t)MROWS * DMODEL * 4);
    unsigned short* y_b   = (unsigned short*)alloc((size_t)MROWS * DMODEL * 2);
    float*          atf   = (float*)alloc((size_t)MROWS * DMODEL * 4);
    float*          fff   = (float*)alloc((size_t)MROWS * DMODEL * 4);
    unsigned short* qkvb  = (unsigned short*)alloc((size_t)3 * MROWS * DMODEL * 2);
    unsigned char*  h8    = (unsigned char*)alloc((size_t)MROWS * FFN_DIM * 2);
    unsigned short* wqkv  = (unsigned short*)alloc((size_t)3 * DMODEL * DMODEL * 2);
    unsigned short* wfc1  = (unsigned short*)alloc((size_t)FFN_DIM * DMODEL * 2);
    unsigned char*  wfc28 = (unsigned char*)alloc((size_t)DMODEL * FFN_DIM);

    unsigned short* vt_b = (unsigned short*)fff;
    float* opart0 = atf;
    float* opart1 = (float*)h8;
    float* lpart  = (float*)x_b;
    unsigned short* fc2p0 = (unsigned short*)fff;
    unsigned short* fc2p1 = (unsigned short*)x_f;

    int n_qkv4 = 3 * DMODEL * DMODEL / 4;
    int n_fc4  = FFN_DIM * DMODEL / 4;
    int cvt_blocks = (n_qkv4 + 2 * n_fc4 + 255) / 256;

    // fused pre-LN + weight conversion (one dispatch; phases overlap)
    ln_pre_cvt<<<dim3(MROWS + cvt_blocks), dim3(256), 0, stream>>>(
        src, pre_gamma, pre_beta, x_f, x_b,
        qkv_w, wqkv, n_qkv4, fc1_w, wfc1, n_fc4, fc2_w, wfc28, n_fc4);

    gemm_lds<3><<<dim3(3 * DMODEL / 128, MROWS / 128), dim3(256), 0, stream>>>(
        x_b, wqkv, qkv_b, qkvb, MROWS, 3 * DMODEL, DMODEL);
    transpose_v<<<dim3(SEQ / 64, BATCH * NH), dim3(256), 0, stream>>>(
        qkvb + (size_t)2 * BATCH * NH * SEQ * HD, vt_b);
    attn_mfma<<<dim3(SEQ / 128, BATCH * NH, 2), dim3(256), 0, stream>>>(
        qkvb, vt_b, opart0, opart1, lpart);
    ln_attn<<<dim3(MROWS), dim3(256), 0, stream>>>(
        opart0, opart1, lpart, lpart + (size_t)BATCH * NH * SEQ,
        x_f, an_gamma, an_beta, y_f, y_b);
    gemm_lds<1><<<dim3(FFN_DIM / 128, MROWS / 128), dim3(256), 0, stream>>>(
        y_b, wfc1, fc1_b, h8, MROWS, FFN_DIM, DMODEL);
    gemm_fp8<<<dim3(DMODEL / 128, MROWS / 128, 2), dim3(256), 0, stream>>>(
        h8, wfc28, fc2p0, fc2p1, MROWS, DMODEL, FFN_DIM, 2048);
    ln_fc2<<<dim3(MROWS), dim3(256), 0, stream>>>(
        fc2p0, fc2p1, fc2_b, y_f, an_gamma, an_beta, out);
}

// Round 10
// 300.294 us; speedup vs baseline: 1.0878x; 1.0506x over previous
//
#include <hip/hip_runtime.h>
#include <hip/hip_bf16.h>
#include <math.h>

#define DMODEL 1024
#define NH 16
#define HD 64
#define SEQ 2048
#define BATCH 2
#define MROWS (BATCH * SEQ)   // 4096
#define FFN_DIM 4096

using bf16x8 = __attribute__((ext_vector_type(8))) __bf16;
using f32x4  = __attribute__((ext_vector_type(4))) float;

typedef const __attribute__((address_space(1))) unsigned char* gas_t;
typedef __attribute__((address_space(3))) unsigned char* las_t;

__device__ inline unsigned short f2bf(float f) {
    unsigned int u = __builtin_bit_cast(unsigned int, f);
    u += 0x7fffu + ((u >> 16) & 1u);   // round-to-nearest-even
    return (unsigned short)(u >> 16);
}
__device__ inline unsigned short f2bf_up(float f) {
    unsigned int u = __builtin_bit_cast(unsigned int, f);
    return (unsigned short)((u + 0x8000u) >> 16);
}
__device__ inline float bf2f(unsigned short u) {
    unsigned int v = ((unsigned int)u) << 16;
    return __builtin_bit_cast(float, v);
}
// tanh-GELU (branch-free): x * sigmoid(1.59577x + 0.0713548x^3); |err| <= ~3e-3
__device__ inline float gelu_f(float x) {
    float x2 = x * x;
    float w = x * fmaf(0.07135481627f, x2, 1.59576912161f);
    return x / (1.0f + __expf(-w));
}

// ---------------- fused: pre-LayerNorm (blocks < MROWS) + weight cvt (rest) ----------------
// qkv/fc1 weights -> bf16; fc2 weights -> fp8 via HW packed cvt
__global__ __launch_bounds__(256) void ln_pre_cvt(
        const float* __restrict__ a,
        const float* __restrict__ gamma, const float* __restrict__ beta,
        float* __restrict__ out_f, unsigned short* __restrict__ out_b,
        const float* __restrict__ wa, unsigned short* __restrict__ oa, int na4,
        const float* __restrict__ wb, unsigned short* __restrict__ ob, int nb4,
        const float* __restrict__ wc, unsigned char* __restrict__ oc, int nc4) {
    int blk = blockIdx.x;
    int t = threadIdx.x;
    if (blk >= MROWS) {
        int i = (blk - MROWS) * 256 + t;
        if (i < na4) {
            float4 v = ((const float4*)wa)[i];
            ushort4 o;
            o.x = f2bf(v.x); o.y = f2bf(v.y); o.z = f2bf(v.z); o.w = f2bf(v.w);
            ((ushort4*)oa)[i] = o;
        } else if (i < na4 + nb4) {
            int j = i - na4;
            float4 v = ((const float4*)wb)[j];
            ushort4 o;
            o.x = f2bf(v.x); o.y = f2bf(v.y); o.z = f2bf(v.z); o.w = f2bf(v.w);
            ((ushort4*)ob)[j] = o;
        } else if (i < na4 + nb4 + nc4) {
            int j = i - na4 - nb4;
            float4 v = ((const float4*)wc)[j];
            int pk = __builtin_amdgcn_cvt_pk_fp8_f32(v.x, v.y, 0, false);
            pk     = __builtin_amdgcn_cvt_pk_fp8_f32(v.z, v.w, pk, true);
            ((unsigned int*)oc)[j] = (unsigned int)pk;
        }
        return;
    }
    int row = blk;
    float4 v = ((const float4*)(a + (size_t)row * DMODEL))[t];
    float s  = v.x + v.y + v.z + v.w;
    float s2 = v.x * v.x + v.y * v.y + v.z * v.z + v.w * v.w;
    #pragma unroll
    for (int off = 32; off > 0; off >>= 1) {
        s  += __shfl_xor(s,  off, 64);
        s2 += __shfl_xor(s2, off, 64);
    }
    __shared__ float red[8];
    int wave = t >> 6, lane = t & 63;
    if (lane == 0) { red[wave] = s; red[4 + wave] = s2; }
    __syncthreads();
    float tot  = red[0] + red[1] + red[2] + red[3];
    float tot2 = red[4] + red[5] + red[6] + red[7];
    float mu   = tot * (1.0f / DMODEL);
    float var  = tot2 * (1.0f / DMODEL) - mu * mu;
    float rstd = rsqrtf(var + 1e-5f);
    float4 g  = ((const float4*)gamma)[t];
    float4 be = ((const float4*)beta)[t];
    float4 o;
    o.x = (v.x - mu) * rstd * g.x + be.x;
    o.y = (v.y - mu) * rstd * g.y + be.y;
    o.z = (v.z - mu) * rstd * g.z + be.z;
    o.w = (v.w - mu) * rstd * g.w + be.w;
    ((float4*)(out_f + (size_t)row * DMODEL))[t] = o;
    ushort4 ob4;
    ob4.x = f2bf(o.x); ob4.y = f2bf(o.y); ob4.z = f2bf(o.z); ob4.w = f2bf(o.w);
    ((ushort4*)(out_b + (size_t)row * DMODEL))[t] = ob4;
}

// ---------------- AddNorm1 fused with attention combine ----------------
__global__ __launch_bounds__(256) void ln_attn(
        const float* __restrict__ o0, const float* __restrict__ o1,
        const float* __restrict__ l0, const float* __restrict__ l1,
        const float* __restrict__ xres,
        const float* __restrict__ gamma, const float* __restrict__ beta,
        float* __restrict__ out_f, unsigned short* __restrict__ out_b) {
    int row = blockIdx.x;
    int t = threadIdx.x;
    int b_ = row >> 11, s = row & 2047;
    int h = t >> 4;
    int bh = b_ * NH + h;
    size_t obase = ((size_t)bh * SEQ + s) * HD + (4 * t & 63);
    float4 va = ((const float4*)(o0 + obase))[0];
    float4 vb = ((const float4*)(o1 + obase))[0];
    float inv_l = 1.0f / (l0[(size_t)bh * SEQ + s] + l1[(size_t)bh * SEQ + s]);
    float4 rr = ((const float4*)(xres + (size_t)row * DMODEL))[t];
    float4 v;
    v.x = (va.x + vb.x) * inv_l + rr.x;
    v.y = (va.y + vb.y) * inv_l + rr.y;
    v.z = (va.z + vb.z) * inv_l + rr.z;
    v.w = (va.w + vb.w) * inv_l + rr.w;

    float s1 = v.x + v.y + v.z + v.w;
    float s2 = v.x * v.x + v.y * v.y + v.z * v.z + v.w * v.w;
    #pragma unroll
    for (int off = 32; off > 0; off >>= 1) {
        s1 += __shfl_xor(s1, off, 64);
        s2 += __shfl_xor(s2, off, 64);
    }
    __shared__ float red[8];
    int wave = t >> 6, lane = t & 63;
    if (lane == 0) { red[wave] = s1; red[4 + wave] = s2; }
    __syncthreads();
    float tot  = red[0] + red[1] + red[2] + red[3];
    float tot2 = red[4] + red[5] + red[6] + red[7];
    float mu   = tot * (1.0f / DMODEL);
    float var  = tot2 * (1.0f / DMODEL) - mu * mu;
    float rstd = rsqrtf(var + 1e-5f);
    float4 g  = ((const float4*)gamma)[t];
    float4 be = ((const float4*)beta)[t];
    float4 o;
    o.x = (v.x - mu) * rstd * g.x + be.x;
    o.y = (v.y - mu) * rstd * g.y + be.y;
    o.z = (v.z - mu) * rstd * g.z + be.z;
    o.w = (v.w - mu) * rstd * g.w + be.w;
    ((float4*)(out_f + (size_t)row * DMODEL))[t] = o;
    ushort4 ob;
    ob.x = f2bf(o.x); ob.y = f2bf(o.y); ob.z = f2bf(o.z); ob.w = f2bf(o.w);
    ((ushort4*)(out_b + (size_t)row * DMODEL))[t] = ob;
}

// ---------------- AddNorm fused with split-K=2 reduction (FC2 epilogue) ----------------
__global__ __launch_bounds__(256) void ln_fc2(
        const unsigned short* __restrict__ p0, const unsigned short* __restrict__ p1,
        const float* __restrict__ bias, const float* __restrict__ resid,
        const float* __restrict__ gamma, const float* __restrict__ beta,
        float* __restrict__ out_f) {
    int row = blockIdx.x;
    int t = threadIdx.x;
    size_t base = (size_t)row * DMODEL;
    ushort4 u0 = ((const ushort4*)(p0 + base))[t];
    ushort4 u1 = ((const ushort4*)(p1 + base))[t];
    float4 bb = ((const float4*)bias)[t];
    float4 rr = ((const float4*)(resid + base))[t];
    float4 v;
    v.x = bf2f(u0.x) + bf2f(u1.x) + bb.x + rr.x;
    v.y = bf2f(u0.y) + bf2f(u1.y) + bb.y + rr.y;
    v.z = bf2f(u0.z) + bf2f(u1.z) + bb.z + rr.z;
    v.w = bf2f(u0.w) + bf2f(u1.w) + bb.w + rr.w;

    float s  = v.x + v.y + v.z + v.w;
    float s2 = v.x * v.x + v.y * v.y + v.z * v.z + v.w * v.w;
    #pragma unroll
    for (int off = 32; off > 0; off >>= 1) {
        s  += __shfl_xor(s,  off, 64);
        s2 += __shfl_xor(s2, off, 64);
    }
    __shared__ float red[8];
    int wave = t >> 6, lane = t & 63;
    if (lane == 0) { red[wave] = s; red[4 + wave] = s2; }
    __syncthreads();
    float tot  = red[0] + red[1] + red[2] + red[3];
    float tot2 = red[4] + red[5] + red[6] + red[7];
    float mu   = tot * (1.0f / DMODEL);
    float var  = tot2 * (1.0f / DMODEL) - mu * mu;
    float rstd = rsqrtf(var + 1e-5f);
    float4 g  = ((const float4*)gamma)[t];
    float4 be = ((const float4*)beta)[t];
    float4 o;
    o.x = (v.x - mu) * rstd * g.x + be.x;
    o.y = (v.y - mu) * rstd * g.y + be.y;
    o.z = (v.z - mu) * rstd * g.z + be.z;
    o.w = (v.w - mu) * rstd * g.w + be.w;
    ((float4*)(out_f + base))[t] = o;
}

// ---------------- LDS-staged bf16 NT GEMM, BK=64, double-buffered 2-phase ----------------
// MODE 1: bias+GELU(tanh) -> fp8 out.
// MODE 3: qkv scatter bf16 (q pre-scaled by 1/8); V blocks (bn>=2048) fuse the
//         transpose: after the K-loop, As/Bs LDS is dead -> scatter acc as [n][m]
//         (stride 132) and store coalesced into vt [bh][d][s]. Bit-identical values
//         to the old transpose_v path (same f2bf(acc+bias)).
template <int MODE>
__global__ __launch_bounds__(256) void gemm_lds(
        const unsigned short* __restrict__ A,
        const unsigned short* __restrict__ Bw,
        const float* __restrict__ bias,
        void* __restrict__ out, void* __restrict__ out2,
        int M, int N, int K) {
    __shared__ unsigned short SMEM[32768];   // As[2][8192] | Bs[2][8192]; reused as scratch

    const int tid  = threadIdx.x;
    const int wave = tid >> 6;
    const int lane = tid & 63;
    const int quad = lane >> 4;
    const int cc   = lane & 15;
    const int bn = blockIdx.x * 128;
    const int bm = blockIdx.y * 128;

    const unsigned short* Ab = A  + (size_t)bm * K;
    const unsigned short* Bb = Bw + (size_t)bn * K;

    const int srow0 = tid >> 3;
    const int sslot = tid & 7;
    const int rsw   = (cc >> 1) & 7;
    const int wm = (wave >> 1) * 64;
    const int wn = (wave & 1) * 64;

    f32x4 acc[4][4] = {};

    auto stage = [&](int buf, int k0) {
        #pragma unroll
        for (int i = 0; i < 4; ++i) {
            int row = i * 32 + srow0;
            int g   = sslot ^ ((row >> 1) & 7);
            const unsigned short* ga = Ab + (size_t)row * K + k0 + g * 8;
            const unsigned short* gb = Bb + (size_t)row * K + k0 + g * 8;
            unsigned short* la = &SMEM[buf * 8192 + i * 2048 + wave * 512];
            unsigned short* lb = &SMEM[16384 + buf * 8192 + i * 2048 + wave * 512];
            __builtin_amdgcn_global_load_lds((gas_t)(const void*)ga, (las_t)(void*)la, 16, 0, 0);
            __builtin_amdgcn_global_load_lds((gas_t)(const void*)gb, (las_t)(void*)lb, 16, 0, 0);
        }
    };

    const int nkt = K >> 6;
    stage(0, 0);
    __syncthreads();          // drains vmcnt(0): buf0 ready

    int cur = 0;
    for (int kt = 0; kt < nkt; ++kt) {
        if (kt + 1 < nkt) stage(cur ^ 1, (kt + 1) << 6);   // prefetch overlaps compute

        bf16x8 af[4][2], bf[4][2];
        #pragma unroll
        for (int mt = 0; mt < 4; ++mt)
            #pragma unroll
            for (int s = 0; s < 2; ++s) {
                int slot = (s * 4 + quad) ^ rsw;
                af[mt][s] = *(const bf16x8*)&SMEM[cur * 8192 + (wm + mt * 16 + cc) * 64 + slot * 8];
            }
        #pragma unroll
        for (int nt = 0; nt < 4; ++nt)
            #pragma unroll
            for (int s = 0; s < 2; ++s) {
                int slot = (s * 4 + quad) ^ rsw;
                bf[nt][s] = *(const bf16x8*)&SMEM[16384 + cur * 8192 + (wn + nt * 16 + cc) * 64 + slot * 8];
            }

        #pragma unroll
        for (int mt = 0; mt < 4; ++mt)
            #pragma unroll
            for (int nt = 0; nt < 4; ++nt) {
                acc[mt][nt] = __builtin_amdgcn_mfma_f32_16x16x32_bf16(
                    af[mt][0], bf[nt][0], acc[mt][nt], 0, 0, 0);
                acc[mt][nt] = __builtin_amdgcn_mfma_f32_16x16x32_bf16(
                    af[mt][1], bf[nt][1], acc[mt][nt], 0, 0, 0);
            }

        if (kt + 1 < nkt) __syncthreads();
        cur ^= 1;
    }

    if constexpr (MODE == 3) {
        if (bn >= 2 * DMODEL) {   // V block: fused transpose via freed staging LDS
            __syncthreads();      // all waves done with SMEM (MFMA reads complete)
            #pragma unroll
            for (int nt = 0; nt < 4; ++nt) {
                int n_loc = wn + nt * 16 + cc;
                float bn_ = bias[bn + n_loc];
                #pragma unroll
                for (int mt = 0; mt < 4; ++mt)
                    #pragma unroll
                    for (int r = 0; r < 4; ++r) {
                        int m_loc = wm + mt * 16 + quad * 4 + r;
                        SMEM[n_loc * 132 + m_loc] = f2bf(acc[mt][nt][r] + bn_);
                    }
            }
            __syncthreads();
            int b_ = bm >> 11;
            int s0 = bm & 2047;
            #pragma unroll
            for (int p = 0; p < 8; ++p) {
                int n_loc  = p * 16 + (tid >> 4);   // 0..127
                int mchunk = tid & 15;
                int rem = (bn + n_loc) & 1023;
                int h = rem >> 6, d = rem & 63;
                size_t vbase = (((size_t)b_ * NH + h) * HD + d) * SEQ + s0 + mchunk * 8;
                uint4 val = *(const uint4*)&SMEM[n_loc * 132 + mchunk * 8];
                *(uint4*)((unsigned short*)out2 + vbase) = val;
            }
            return;
        }
    }

    #pragma unroll
    for (int mt = 0; mt < 4; ++mt)
        #pragma unroll
        for (int nt = 0; nt < 4; ++nt) {
            if constexpr (MODE == 1) {
                int m0 = bm + wm + mt * 16 + quad * 4;
                int n  = bn + wn + nt * 16 + cc;
                float bn_ = bias[n];
                float v0 = gelu_f(acc[mt][nt][0] + bn_);
                float v1 = gelu_f(acc[mt][nt][1] + bn_);
                float v2 = gelu_f(acc[mt][nt][2] + bn_);
                float v3 = gelu_f(acc[mt][nt][3] + bn_);
                int pk = __builtin_amdgcn_cvt_pk_fp8_f32(v0, v1, 0, false);
                pk     = __builtin_amdgcn_cvt_pk_fp8_f32(v2, v3, pk, true);
                unsigned char* o = (unsigned char*)out + (size_t)m0 * N + n;
                o[0]             = (unsigned char)pk;
                o[(size_t)N]     = (unsigned char)(pk >> 8);
                o[(size_t)2 * N] = (unsigned char)(pk >> 16);
                o[(size_t)3 * N] = (unsigned char)(pk >> 24);
            } else {   // MODE 3, q/k blocks
                #pragma unroll
                for (int r = 0; r < 4; ++r) {
                    int m = bm + wm + mt * 16 + quad * 4 + r;
                    int n = bn + wn + nt * 16 + cc;
                    float v = acc[mt][nt][r] + bias[n];
                    int b_ = m >> 11, srow = m & 2047;
                    int which = n >> 10, rem = n & 1023;
                    int h = rem >> 6, d = rem & 63;
                    if (which == 0) v *= 0.125f;   // fold 1/sqrt(HD) into Q
                    size_t idx = ((((size_t)which * BATCH + b_) * NH + h) * SEQ + srow) * HD + d;
                    ((unsigned short*)out)[idx] = f2bf(v);
                }
            }
        }
}

// ---------------- fp8 NT GEMM (FC2 split-K=2): 3-buffer depth-2 counted-vmcnt pipeline ----
__global__ __launch_bounds__(256) void gemm_fp8(
        const unsigned char* __restrict__ A,
        const unsigned char* __restrict__ Bw,
        unsigned short* __restrict__ p0, unsigned short* __restrict__ p1,
        int M, int N, int K, int KC) {
    __shared__ unsigned char As[3][128 * 64];   // 3 x 8 KB
    __shared__ unsigned char Bs[3][128 * 64];   // 3 x 8 KB

    const int tid  = threadIdx.x;
    const int wave = tid >> 6;
    const int lane = tid & 63;
    const int quad = lane >> 4;
    const int cc   = lane & 15;
    const int bn = blockIdx.x * 128;
    const int bm = blockIdx.y * 128;

    const unsigned char* Ab = A  + (size_t)bm * K;
    const unsigned char* Bb = Bw + (size_t)bn * K;

    const int srow0 = tid >> 2;
    const int schunk = tid & 3;
    const int rsw = (cc >> 1) & 3;
    const int wm = (wave >> 1) * 64;
    const int wn = (wave & 1) * 64;

    const int kbeg = blockIdx.z * KC;

    f32x4 acc[4][4] = {};

    auto stage = [&](int buf, int k0) {
        #pragma unroll
        for (int i = 0; i < 2; ++i) {
            int row = i * 64 + srow0;
            int g   = schunk ^ ((row >> 1) & 3);
            const unsigned char* ga = Ab + (size_t)row * K + k0 + g * 16;
            const unsigned char* gb = Bb + (size_t)row * K + k0 + g * 16;
            unsigned char* la = &As[buf][i * 4096 + wave * 1024];
            unsigned char* lb = &Bs[buf][i * 4096 + wave * 1024];
            __builtin_amdgcn_global_load_lds((gas_t)(const void*)ga, (las_t)(void*)la, 16, 0, 0);
            __builtin_amdgcn_global_load_lds((gas_t)(const void*)gb, (las_t)(void*)lb, 16, 0, 0);
        }
    };

    const int nkt = KC >> 6;   // 32 for KC=2048
    stage(0, kbeg);
    if (nkt > 1) {
        stage(1, kbeg + 64);
        asm volatile("s_waitcnt vmcnt(4)" ::: "memory");   // buf0 landed; buf1 in flight
    } else {
        asm volatile("s_waitcnt vmcnt(0)" ::: "memory");
    }
    __builtin_amdgcn_s_barrier();

    int cur = 0;
    for (int kt = 0; kt < nkt; ++kt) {
        int pbuf = cur + 2; if (pbuf >= 3) pbuf -= 3;      // (cur+2)%3
        if (kt + 2 < nkt) stage(pbuf, kbeg + ((kt + 2) << 6));

        long af[4][2], bf[4][2];
        #pragma unroll
        for (int mt = 0; mt < 4; ++mt)
            #pragma unroll
            for (int s = 0; s < 2; ++s) {
                int slot = ((quad >> 1) + 2 * s) ^ rsw;
                af[mt][s] = *(const long*)&As[cur][(wm + mt * 16 + cc) * 64 + slot * 16 + (quad & 1) * 8];
            }
        #pragma unroll
        for (int nt = 0; nt < 4; ++nt)
            #pragma unroll
            for (int s = 0; s < 2; ++s) {
                int slot = ((quad >> 1) + 2 * s) ^ rsw;
                bf[nt][s] = *(const long*)&Bs[cur][(wn + nt * 16 + cc) * 64 + slot * 16 + (quad & 1) * 8];
            }

        #pragma unroll
        for (int mt = 0; mt < 4; ++mt)
            #pragma unroll
            for (int nt = 0; nt < 4; ++nt) {
                acc[mt][nt] = __builtin_amdgcn_mfma_f32_16x16x32_fp8_fp8(
                    af[mt][0], bf[nt][0], acc[mt][nt], 0, 0, 0);
                acc[mt][nt] = __builtin_amdgcn_mfma_f32_16x16x32_fp8_fp8(
                    af[mt][1], bf[nt][1], acc[mt][nt], 0, 0, 0);
            }

        if (kt + 1 < nkt) {
            asm volatile("s_waitcnt lgkmcnt(0)" ::: "memory");   // my LDS reads done
            if (kt + 2 < nkt)
                asm volatile("s_waitcnt vmcnt(4)" ::: "memory"); // kt+1 landed; kt+2 in flight
            else
                asm volatile("s_waitcnt vmcnt(0)" ::: "memory"); // tail: drain final tile
            __builtin_amdgcn_s_barrier();
        }
        cur = (cur < 2) ? cur + 1 : 0;
    }

    unsigned short* outp = (blockIdx.z == 0) ? p0 : p1;
    #pragma unroll
    for (int mt = 0; mt < 4; ++mt)
        #pragma unroll
        for (int nt = 0; nt < 4; ++nt)
            #pragma unroll
            for (int r = 0; r < 4; ++r) {
                int m = bm + wm + mt * 16 + quad * 4 + r;
                int n = bn + wn + nt * 16 + cc;
                outp[(size_t)m * N + n] = f2bf(acc[mt][nt][r]);
            }
}

// ---------------- MFMA flash attention v12: v11 + T5 setprio around MFMA clusters -------
#define KPAD 72
__global__ __launch_bounds__(256, 4) void attn_mfma(
        const unsigned short* __restrict__ qkv,
        const unsigned short* __restrict__ vt,
        float* __restrict__ op0, float* __restrict__ op1,
        float* __restrict__ lpart) {
    const int tid  = threadIdx.x;
    const int wave = tid >> 6;
    const int lane = tid & 63;
    const int quad = lane >> 4;
    const int cc   = lane & 15;
    const int qblk = blockIdx.x;
    const int bh   = blockIdx.y;
    const int half = blockIdx.z;

    const size_t headsz = (size_t)SEQ * HD;
    const unsigned short* qb  = qkv + (size_t)bh * headsz;
    const unsigned short* kb  = qkv + ((size_t)BATCH * NH + bh) * headsz;
    const unsigned short* vtb = vt + (size_t)bh * headsz;
    float* opart = half ? op1 : op0;
    float* lp    = lpart + (size_t)half * BATCH * NH * SEQ;

    __shared__ unsigned short Ks[64 * 64];       // 8 KB, swizzled
    __shared__ unsigned short Vt[64 * 64];       // 8 KB, swizzled
    __shared__ unsigned short Ps[4 * 32 * KPAD]; // 18 KB, v6 layout

    bf16x8 qa[2][2];
    #pragma unroll
    for (int mt = 0; mt < 2; ++mt) {
        const unsigned short* qp =
            qb + (size_t)(qblk * 128 + wave * 32 + mt * 16 + cc) * HD + quad * 8;
        qa[mt][0] = *(const bf16x8*)qp;
        qa[mt][1] = *(const bf16x8*)(qp + 32);
    }

    f32x4 o_acc[2][4] = {};
    float l_i[2][4] = {};

    // staging geometry: 8 lanes per row, rows srow0 and srow0+8
    const int srow0 = wave * 16 + (lane >> 3);
    const int sc8c  = lane & 7;                      // logical 16B chunk
    const int swz   = (sc8c ^ (lane >> 3)) * 8;      // phys chunk offset (row&7 == lane>>3)
    const int psw   = (cc >> 2) & 3;
    const int rw7   = cc & 7;                        // fragment row & 7 for reads

    const int kt0 = half * 16, ktend = kt0 + 16;

    // prologue prefetch: named scalars (rule #20 — no arrays, no conditional defs)
    uint4 ka0, ka1, va0, va1;
    {
        const unsigned short* kp0 = &kb[(size_t)(kt0 * 64 + srow0) * HD + sc8c * 8];
        const unsigned short* vp0 = &vtb[(size_t)srow0 * SEQ + kt0 * 64 + sc8c * 8];
        ka0 = *(const uint4*)kp0;
        ka1 = *(const uint4*)(kp0 + 8 * HD);     // row srow0+8
        va0 = *(const uint4*)vp0;
        va1 = *(const uint4*)(vp0 + 8 * SEQ);    // row srow0+8
    }

    for (int kt = kt0; kt < ktend; ++kt) {
        __syncthreads();   // prev readers done
        *(uint4*)&Ks[srow0 * 64 + swz]        = ka0;
        *(uint4*)&Ks[(srow0 + 8) * 64 + swz]  = ka1;
        *(uint4*)&Vt[srow0 * 64 + swz]        = va0;
        *(uint4*)&Vt[(srow0 + 8) * 64 + swz]  = va1;
        __syncthreads();   // tile visible

        // issue next-tile loads NOW (unconditional, clamped) — hide under compute
        int ktn = (kt + 1 < ktend) ? kt + 1 : kt;
        const unsigned short* kpn = &kb[(size_t)(ktn * 64 + srow0) * HD + sc8c * 8];
        const unsigned short* vpn = &vtb[(size_t)srow0 * SEQ + ktn * 64 + sc8c * 8];
        uint4 nk0 = *(const uint4*)kpn;
        uint4 nk1 = *(const uint4*)(kpn + 8 * HD);
        uint4 nv0 = *(const uint4*)vpn;
        uint4 nv1 = *(const uint4*)(vpn + 8 * SEQ);

        f32x4 s_acc[2][4];
        __builtin_amdgcn_s_setprio(1);
        #pragma unroll
        for (int nt = 0; nt < 4; ++nt) {
            const unsigned short* kp = &Ks[(nt * 16 + cc) * 64];
            bf16x8 kf0 = *(const bf16x8*)&kp[(quad ^ rw7) * 8];
            bf16x8 kf1 = *(const bf16x8*)&kp[((quad + 4) ^ rw7) * 8];
            #pragma unroll
            for (int mt = 0; mt < 2; ++mt) {
                f32x4 z = {};
                z = __builtin_amdgcn_mfma_f32_16x16x32_bf16(qa[mt][0], kf0, z, 0, 0, 0);
                s_acc[mt][nt] = __builtin_amdgcn_mfma_f32_16x16x32_bf16(qa[mt][1], kf1, z, 0, 0, 0);
            }
        }
        __builtin_amdgcn_s_setprio(0);

        unsigned short* pw = &Ps[wave * 32 * KPAD];
        #pragma unroll
        for (int mt = 0; mt < 2; ++mt)
            #pragma unroll
            for (int nt = 0; nt < 4; ++nt) {
                int pc = ((nt ^ quad) & 3) * 16 + cc;
                #pragma unroll
                for (int r = 0; r < 4; ++r) {
                    float e = __expf(s_acc[mt][nt][r]);
                    l_i[mt][r] += e;
                    pw[(mt * 16 + quad * 4 + r) * KPAD + pc] = f2bf_up(e);
                }
            }

        bf16x8 pf[2][2];
        #pragma unroll
        for (int mt = 0; mt < 2; ++mt) {
            const unsigned short* pa = &pw[(mt * 16 + cc) * KPAD];
            pf[mt][0] = *(const bf16x8*)&pa[((((quad >> 1))     ^ psw) & 3) * 16 + (quad & 1) * 8];
            pf[mt][1] = *(const bf16x8*)&pa[(((2 + (quad >> 1)) ^ psw) & 3) * 16 + (quad & 1) * 8];
        }

        __builtin_amdgcn_s_setprio(1);
        #pragma unroll
        for (int nt = 0; nt < 4; ++nt) {
            const unsigned short* vp = &Vt[(nt * 16 + cc) * 64];
            bf16x8 vf0 = *(const bf16x8*)&vp[(quad ^ rw7) * 8];
            bf16x8 vf1 = *(const bf16x8*)&vp[((quad + 4) ^ rw7) * 8];
            #pragma unroll
            for (int mt = 0; mt < 2; ++mt) {
                o_acc[mt][nt] = __builtin_amdgcn_mfma_f32_16x16x32_bf16(
                    pf[mt][0], vf0, o_acc[mt][nt], 0, 0, 0);
                o_acc[mt][nt] = __builtin_amdgcn_mfma_f32_16x16x32_bf16(
                    pf[mt][1], vf1, o_acc[mt][nt], 0, 0, 0);
            }
        }
        __builtin_amdgcn_s_setprio(0);

        ka0 = nk0; ka1 = nk1; va0 = nv0; va1 = nv1;   // register moves
    }

    #pragma unroll
    for (int mt = 0; mt < 2; ++mt) {
        float lr[4];
        #pragma unroll
        for (int r = 0; r < 4; ++r) {
            float l = l_i[mt][r];
            #pragma unroll
            for (int off = 1; off < 16; off <<= 1)
                l += __shfl_xor(l, off, 64);
            lr[r] = l;
        }
        int rowbase = qblk * 128 + wave * 32 + mt * 16;
        if (cc == 0) {
            float4 lv = {lr[0], lr[1], lr[2], lr[3]};
            *(float4*)&lp[(size_t)bh * SEQ + rowbase + quad * 4] = lv;
        }
        #pragma unroll
        for (int nt = 0; nt < 4; ++nt)
            #pragma unroll
            for (int r = 0; r < 4; ++r) {
                int row = rowbase + quad * 4 + r;
                opart[((size_t)bh * SEQ + row) * HD + nt * 16 + cc] = o_acc[mt][nt][r];
            }
    }
}

extern "C" void kernel_launch(void* const* d_in, const int* in_sizes, int n_in,
                              void* d_out, int out_size, void* d_ws, size_t ws_size,
                              hipStream_t stream) {
    const float* src       = (const float*)d_in[0];
    const float* pre_gamma = (const float*)d_in[1];
    const float* pre_beta  = (const float*)d_in[2];
    const float* qkv_w     = (const float*)d_in[3];
    const float* qkv_b     = (const float*)d_in[4];
    const float* an_gamma  = (const float*)d_in[5];
    const float* an_beta   = (const float*)d_in[6];
    const float* fc1_w     = (const float*)d_in[7];
    const float* fc1_b     = (const float*)d_in[8];
    const float* fc2_w     = (const float*)d_in[9];
    const float* fc2_b     = (const float*)d_in[10];
    float* out = (float*)d_out;

    char* ws = (char*)d_ws;
    size_t off = 0;
    auto alloc = [&](size_t bytes) {
        char* p = ws + off;
        off += (bytes + 255) & ~(size_t)255;
        return p;
    };
    float*          x_f   = (float*)alloc((size_t)MROWS * DMODEL * 4);
    unsigned short* x_b   = (unsigned short*)alloc((size_t)MROWS * DMODEL * 2);
    float*          y_f   = (float*)alloc((size_t)MROWS * DMODEL * 4);
    unsigned short* y_b   = (unsigned short*)alloc((size_t)MROWS * DMODEL * 2);
    float*          atf   = (float*)alloc((size_t)MROWS * DMODEL * 4);
    float*          fff   = (float*)alloc((size_t)MROWS * DMODEL * 4);
    unsigned short* qkvb  = (unsigned short*)alloc((size_t)3 * MROWS * DMODEL * 2);
    unsigned char*  h8    = (unsigned char*)alloc((size_t)MROWS * FFN_DIM * 2);
    unsigned short* wqkv  = (unsigned short*)alloc((size_t)3 * DMODEL * DMODEL * 2);
    unsigned short* wfc1  = (unsigned short*)alloc((size_t)FFN_DIM * DMODEL * 2);
    unsigned char*  wfc28 = (unsigned char*)alloc((size_t)DMODEL * FFN_DIM);

    unsigned short* vt_b = (unsigned short*)fff;
    float* opart0 = atf;
    float* opart1 = (float*)h8;
    float* lpart  = (float*)x_b;
    unsigned short* fc2p0 = (unsigned short*)fff;
    unsigned short* fc2p1 = (unsigned short*)x_f;

    int n_qkv4 = 3 * DMODEL * DMODEL / 4;
    int n_fc4  = FFN_DIM * DMODEL / 4;
    int cvt_blocks = (n_qkv4 + 2 * n_fc4 + 255) / 256;

    // fused pre-LN + weight conversion (one dispatch; phases overlap)
    ln_pre_cvt<<<dim3(MROWS + cvt_blocks), dim3(256), 0, stream>>>(
        src, pre_gamma, pre_beta, x_f, x_b,
        qkv_w, wqkv, n_qkv4, fc1_w, wfc1, n_fc4, fc2_w, wfc28, n_fc4);

    // QKV GEMM: q/k scatter to qkvb; V blocks write vt_b directly (fused transpose)
    gemm_lds<3><<<dim3(3 * DMODEL / 128, MROWS / 128), dim3(256), 0, stream>>>(
        x_b, wqkv, qkv_b, qkvb, vt_b, MROWS, 3 * DMODEL, DMODEL);
    attn_mfma<<<dim3(SEQ / 128, BATCH * NH, 2), dim3(256), 0, stream>>>(
        qkvb, vt_b, opart0, opart1, lpart);
    ln_attn<<<dim3(MROWS), dim3(256), 0, stream>>>(
        opart0, opart1, lpart, lpart + (size_t)BATCH * NH * SEQ,
        x_f, an_gamma, an_beta, y_f, y_b);
    gemm_lds<1><<<dim3(FFN_DIM / 128, MROWS / 128), dim3(256), 0, stream>>>(
        y_b, wfc1, fc1_b, h8, nullptr, MROWS, FFN_DIM, DMODEL);
    gemm_fp8<<<dim3(DMODEL / 128, MROWS / 128, 2), dim3(256), 0, stream>>>(
        h8, wfc28, fc2p0, fc2p1, MROWS, DMODEL, FFN_DIM, 2048);
    ln_fc2<<<dim3(MROWS), dim3(256), 0, stream>>>(
        fc2p0, fc2p1, fc2_b, y_f, an_gamma, an_beta, out);
}

// Round 11
// 297.592 us; speedup vs baseline: 1.0977x; 1.0091x over previous
//
#include <hip/hip_runtime.h>
#include <hip/hip_bf16.h>
#include <math.h>

#define DMODEL 1024
#define NH 16
#define HD 64
#define SEQ 2048
#define BATCH 2
#define MROWS (BATCH * SEQ)   // 4096
#define FFN_DIM 4096

using bf16x8 = __attribute__((ext_vector_type(8))) __bf16;
using f32x4  = __attribute__((ext_vector_type(4))) float;

typedef const __attribute__((address_space(1))) unsigned char* gas_t;
typedef __attribute__((address_space(3))) unsigned char* las_t;

__device__ inline unsigned short f2bf(float f) {
    unsigned int u = __builtin_bit_cast(unsigned int, f);
    u += 0x7fffu + ((u >> 16) & 1u);   // round-to-nearest-even
    return (unsigned short)(u >> 16);
}
__device__ inline unsigned short f2bf_up(float f) {
    unsigned int u = __builtin_bit_cast(unsigned int, f);
    return (unsigned short)((u + 0x8000u) >> 16);
}
__device__ inline float bf2f(unsigned short u) {
    unsigned int v = ((unsigned int)u) << 16;
    return __builtin_bit_cast(float, v);
}
// tanh-GELU (branch-free): x * sigmoid(1.59577x + 0.0713548x^3); |err| <= ~3e-3
__device__ inline float gelu_f(float x) {
    float x2 = x * x;
    float w = x * fmaf(0.07135481627f, x2, 1.59576912161f);
    return x / (1.0f + __expf(-w));
}

// ---------------- fused: pre-LayerNorm (blocks < MROWS) + weight cvt (rest) ----------------
// qkv/fc1 weights -> bf16; fc2 weights -> fp8 via HW packed cvt
__global__ __launch_bounds__(256) void ln_pre_cvt(
        const float* __restrict__ a,
        const float* __restrict__ gamma, const float* __restrict__ beta,
        float* __restrict__ out_f, unsigned short* __restrict__ out_b,
        const float* __restrict__ wa, unsigned short* __restrict__ oa, int na4,
        const float* __restrict__ wb, unsigned short* __restrict__ ob, int nb4,
        const float* __restrict__ wc, unsigned char* __restrict__ oc, int nc4) {
    int blk = blockIdx.x;
    int t = threadIdx.x;
    if (blk >= MROWS) {
        int i = (blk - MROWS) * 256 + t;
        if (i < na4) {
            float4 v = ((const float4*)wa)[i];
            ushort4 o;
            o.x = f2bf(v.x); o.y = f2bf(v.y); o.z = f2bf(v.z); o.w = f2bf(v.w);
            ((ushort4*)oa)[i] = o;
        } else if (i < na4 + nb4) {
            int j = i - na4;
            float4 v = ((const float4*)wb)[j];
            ushort4 o;
            o.x = f2bf(v.x); o.y = f2bf(v.y); o.z = f2bf(v.z); o.w = f2bf(v.w);
            ((ushort4*)ob)[j] = o;
        } else if (i < na4 + nb4 + nc4) {
            int j = i - na4 - nb4;
            float4 v = ((const float4*)wc)[j];
            int pk = __builtin_amdgcn_cvt_pk_fp8_f32(v.x, v.y, 0, false);
            pk     = __builtin_amdgcn_cvt_pk_fp8_f32(v.z, v.w, pk, true);
            ((unsigned int*)oc)[j] = (unsigned int)pk;
        }
        return;
    }
    int row = blk;
    float4 v = ((const float4*)(a + (size_t)row * DMODEL))[t];
    float s  = v.x + v.y + v.z + v.w;
    float s2 = v.x * v.x + v.y * v.y + v.z * v.z + v.w * v.w;
    #pragma unroll
    for (int off = 32; off > 0; off >>= 1) {
        s  += __shfl_xor(s,  off, 64);
        s2 += __shfl_xor(s2, off, 64);
    }
    __shared__ float red[8];
    int wave = t >> 6, lane = t & 63;
    if (lane == 0) { red[wave] = s; red[4 + wave] = s2; }
    __syncthreads();
    float tot  = red[0] + red[1] + red[2] + red[3];
    float tot2 = red[4] + red[5] + red[6] + red[7];
    float mu   = tot * (1.0f / DMODEL);
    float var  = tot2 * (1.0f / DMODEL) - mu * mu;
    float rstd = rsqrtf(var + 1e-5f);
    float4 g  = ((const float4*)gamma)[t];
    float4 be = ((const float4*)beta)[t];
    float4 o;
    o.x = (v.x - mu) * rstd * g.x + be.x;
    o.y = (v.y - mu) * rstd * g.y + be.y;
    o.z = (v.z - mu) * rstd * g.z + be.z;
    o.w = (v.w - mu) * rstd * g.w + be.w;
    ((float4*)(out_f + (size_t)row * DMODEL))[t] = o;
    ushort4 ob4;
    ob4.x = f2bf(o.x); ob4.y = f2bf(o.y); ob4.z = f2bf(o.z); ob4.w = f2bf(o.w);
    ((ushort4*)(out_b + (size_t)row * DMODEL))[t] = ob4;
}

// ---------------- AddNorm1 fused with attention combine ----------------
__global__ __launch_bounds__(256) void ln_attn(
        const float* __restrict__ o0, const float* __restrict__ o1,
        const float* __restrict__ l0, const float* __restrict__ l1,
        const float* __restrict__ xres,
        const float* __restrict__ gamma, const float* __restrict__ beta,
        float* __restrict__ out_f, unsigned short* __restrict__ out_b) {
    int row = blockIdx.x;
    int t = threadIdx.x;
    int b_ = row >> 11, s = row & 2047;
    int h = t >> 4;
    int bh = b_ * NH + h;
    size_t obase = ((size_t)bh * SEQ + s) * HD + (4 * t & 63);
    float4 va = ((const float4*)(o0 + obase))[0];
    float4 vb = ((const float4*)(o1 + obase))[0];
    float inv_l = 1.0f / (l0[(size_t)bh * SEQ + s] + l1[(size_t)bh * SEQ + s]);
    float4 rr = ((const float4*)(xres + (size_t)row * DMODEL))[t];
    float4 v;
    v.x = (va.x + vb.x) * inv_l + rr.x;
    v.y = (va.y + vb.y) * inv_l + rr.y;
    v.z = (va.z + vb.z) * inv_l + rr.z;
    v.w = (va.w + vb.w) * inv_l + rr.w;

    float s1 = v.x + v.y + v.z + v.w;
    float s2 = v.x * v.x + v.y * v.y + v.z * v.z + v.w * v.w;
    #pragma unroll
    for (int off = 32; off > 0; off >>= 1) {
        s1 += __shfl_xor(s1, off, 64);
        s2 += __shfl_xor(s2, off, 64);
    }
    __shared__ float red[8];
    int wave = t >> 6, lane = t & 63;
    if (lane == 0) { red[wave] = s1; red[4 + wave] = s2; }
    __syncthreads();
    float tot  = red[0] + red[1] + red[2] + red[3];
    float tot2 = red[4] + red[5] + red[6] + red[7];
    float mu   = tot * (1.0f / DMODEL);
    float var  = tot2 * (1.0f / DMODEL) - mu * mu;
    float rstd = rsqrtf(var + 1e-5f);
    float4 g  = ((const float4*)gamma)[t];
    float4 be = ((const float4*)beta)[t];
    float4 o;
    o.x = (v.x - mu) * rstd * g.x + be.x;
    o.y = (v.y - mu) * rstd * g.y + be.y;
    o.z = (v.z - mu) * rstd * g.z + be.z;
    o.w = (v.w - mu) * rstd * g.w + be.w;
    ((float4*)(out_f + (size_t)row * DMODEL))[t] = o;
    ushort4 ob;
    ob.x = f2bf(o.x); ob.y = f2bf(o.y); ob.z = f2bf(o.z); ob.w = f2bf(o.w);
    ((ushort4*)(out_b + (size_t)row * DMODEL))[t] = ob;
}

// ---------------- AddNorm fused with split-K=2 reduction (FC2 epilogue) ----------------
__global__ __launch_bounds__(256) void ln_fc2(
        const unsigned short* __restrict__ p0, const unsigned short* __restrict__ p1,
        const float* __restrict__ bias, const float* __restrict__ resid,
        const float* __restrict__ gamma, const float* __restrict__ beta,
        float* __restrict__ out_f) {
    int row = blockIdx.x;
    int t = threadIdx.x;
    size_t base = (size_t)row * DMODEL;
    ushort4 u0 = ((const ushort4*)(p0 + base))[t];
    ushort4 u1 = ((const ushort4*)(p1 + base))[t];
    float4 bb = ((const float4*)bias)[t];
    float4 rr = ((const float4*)(resid + base))[t];
    float4 v;
    v.x = bf2f(u0.x) + bf2f(u1.x) + bb.x + rr.x;
    v.y = bf2f(u0.y) + bf2f(u1.y) + bb.y + rr.y;
    v.z = bf2f(u0.z) + bf2f(u1.z) + bb.z + rr.z;
    v.w = bf2f(u0.w) + bf2f(u1.w) + bb.w + rr.w;

    float s  = v.x + v.y + v.z + v.w;
    float s2 = v.x * v.x + v.y * v.y + v.z * v.z + v.w * v.w;
    #pragma unroll
    for (int off = 32; off > 0; off >>= 1) {
        s  += __shfl_xor(s,  off, 64);
        s2 += __shfl_xor(s2, off, 64);
    }
    __shared__ float red[8];
    int wave = t >> 6, lane = t & 63;
    if (lane == 0) { red[wave] = s; red[4 + wave] = s2; }
    __syncthreads();
    float tot  = red[0] + red[1] + red[2] + red[3];
    float tot2 = red[4] + red[5] + red[6] + red[7];
    float mu   = tot * (1.0f / DMODEL);
    float var  = tot2 * (1.0f / DMODEL) - mu * mu;
    float rstd = rsqrtf(var + 1e-5f);
    float4 g  = ((const float4*)gamma)[t];
    float4 be = ((const float4*)beta)[t];
    float4 o;
    o.x = (v.x - mu) * rstd * g.x + be.x;
    o.y = (v.y - mu) * rstd * g.y + be.y;
    o.z = (v.z - mu) * rstd * g.z + be.z;
    o.w = (v.w - mu) * rstd * g.w + be.w;
    ((float4*)(out_f + base))[t] = o;
}

// ---------------- LDS-staged bf16 NT GEMM, BK=64, double-buffered 2-phase ----------------
// T1 XCD swizzle: 1-D grid; XCD (bid&7) owns an 8-row x (gx/2)-col slab of the tile
// grid -> resident working set ~4MB (8 A-panels + 8 B-panels) fits the XCD L2, so
// staged loads hit L2 (~200cy) instead of HBM (~900cy), shrinking the barrier drain.
// Pure block permutation: per-block math unchanged -> bit-identical output.
// MODE 1: bias+GELU(tanh) -> fp8 out.
// MODE 3: qkv scatter bf16 (q pre-scaled by 1/8); V blocks (bn>=2048) fuse the
//         transpose via freed staging LDS.
template <int MODE>
__global__ __launch_bounds__(256) void gemm_lds(
        const unsigned short* __restrict__ A,
        const unsigned short* __restrict__ Bw,
        const float* __restrict__ bias,
        void* __restrict__ out, void* __restrict__ out2,
        int M, int N, int K) {
    __shared__ unsigned short SMEM[32768];   // As[2][8192] | Bs[2][8192]; reused as scratch

    const int tid  = threadIdx.x;
    const int wave = tid >> 6;
    const int lane = tid & 63;
    const int quad = lane >> 4;
    const int cc   = lane & 15;

    // XCD-slab decode: grid = gy x gx tiles, gy%4==0, gx%2==0 (32x32 FC1, 32x24 QKV)
    const int gx = N >> 7;
    const int slab_cols = gx >> 1;          // 16 (FC1) / 12 (QKV)
    const int slab_rows = (M >> 7) >> 2;    // 8
    const int bid = blockIdx.x;
    const int xcd = bid & 7;
    const int idx = bid >> 3;
    const int local_c = idx % slab_cols;
    const int local_r = idx / slab_cols;
    const int bn = ((xcd & 1) * slab_cols + local_c) << 7;
    const int bm = (((xcd >> 1) * slab_rows) + local_r) << 7;

    const unsigned short* Ab = A  + (size_t)bm * K;
    const unsigned short* Bb = Bw + (size_t)bn * K;

    const int srow0 = tid >> 3;
    const int sslot = tid & 7;
    const int rsw   = (cc >> 1) & 7;
    const int wm = (wave >> 1) * 64;
    const int wn = (wave & 1) * 64;

    f32x4 acc[4][4] = {};

    auto stage = [&](int buf, int k0) {
        #pragma unroll
        for (int i = 0; i < 4; ++i) {
            int row = i * 32 + srow0;
            int g   = sslot ^ ((row >> 1) & 7);
            const unsigned short* ga = Ab + (size_t)row * K + k0 + g * 8;
            const unsigned short* gb = Bb + (size_t)row * K + k0 + g * 8;
            unsigned short* la = &SMEM[buf * 8192 + i * 2048 + wave * 512];
            unsigned short* lb = &SMEM[16384 + buf * 8192 + i * 2048 + wave * 512];
            __builtin_amdgcn_global_load_lds((gas_t)(const void*)ga, (las_t)(void*)la, 16, 0, 0);
            __builtin_amdgcn_global_load_lds((gas_t)(const void*)gb, (las_t)(void*)lb, 16, 0, 0);
        }
    };

    const int nkt = K >> 6;
    stage(0, 0);
    __syncthreads();          // drains vmcnt(0): buf0 ready

    int cur = 0;
    for (int kt = 0; kt < nkt; ++kt) {
        if (kt + 1 < nkt) stage(cur ^ 1, (kt + 1) << 6);   // prefetch overlaps compute

        bf16x8 af[4][2], bf[4][2];
        #pragma unroll
        for (int mt = 0; mt < 4; ++mt)
            #pragma unroll
            for (int s = 0; s < 2; ++s) {
                int slot = (s * 4 + quad) ^ rsw;
                af[mt][s] = *(const bf16x8*)&SMEM[cur * 8192 + (wm + mt * 16 + cc) * 64 + slot * 8];
            }
        #pragma unroll
        for (int nt = 0; nt < 4; ++nt)
            #pragma unroll
            for (int s = 0; s < 2; ++s) {
                int slot = (s * 4 + quad) ^ rsw;
                bf[nt][s] = *(const bf16x8*)&SMEM[16384 + cur * 8192 + (wn + nt * 16 + cc) * 64 + slot * 8];
            }

        #pragma unroll
        for (int mt = 0; mt < 4; ++mt)
            #pragma unroll
            for (int nt = 0; nt < 4; ++nt) {
                acc[mt][nt] = __builtin_amdgcn_mfma_f32_16x16x32_bf16(
                    af[mt][0], bf[nt][0], acc[mt][nt], 0, 0, 0);
                acc[mt][nt] = __builtin_amdgcn_mfma_f32_16x16x32_bf16(
                    af[mt][1], bf[nt][1], acc[mt][nt], 0, 0, 0);
            }

        if (kt + 1 < nkt) __syncthreads();
        cur ^= 1;
    }

    if constexpr (MODE == 3) {
        if (bn >= 2 * DMODEL) {   // V block: fused transpose via freed staging LDS
            __syncthreads();      // all waves done with SMEM (MFMA reads complete)
            #pragma unroll
            for (int nt = 0; nt < 4; ++nt) {
                int n_loc = wn + nt * 16 + cc;
                float bn_ = bias[bn + n_loc];
                #pragma unroll
                for (int mt = 0; mt < 4; ++mt)
                    #pragma unroll
                    for (int r = 0; r < 4; ++r) {
                        int m_loc = wm + mt * 16 + quad * 4 + r;
                        SMEM[n_loc * 132 + m_loc] = f2bf(acc[mt][nt][r] + bn_);
                    }
            }
            __syncthreads();
            int b_ = bm >> 11;
            int s0 = bm & 2047;
            #pragma unroll
            for (int p = 0; p < 8; ++p) {
                int n_loc  = p * 16 + (tid >> 4);   // 0..127
                int mchunk = tid & 15;
                int rem = (bn + n_loc) & 1023;
                int h = rem >> 6, d = rem & 63;
                size_t vbase = (((size_t)b_ * NH + h) * HD + d) * SEQ + s0 + mchunk * 8;
                uint4 val = *(const uint4*)&SMEM[n_loc * 132 + mchunk * 8];
                *(uint4*)((unsigned short*)out2 + vbase) = val;
            }
            return;
        }
    }

    #pragma unroll
    for (int mt = 0; mt < 4; ++mt)
        #pragma unroll
        for (int nt = 0; nt < 4; ++nt) {
            if constexpr (MODE == 1) {
                int m0 = bm + wm + mt * 16 + quad * 4;
                int n  = bn + wn + nt * 16 + cc;
                float bn_ = bias[n];
                float v0 = gelu_f(acc[mt][nt][0] + bn_);
                float v1 = gelu_f(acc[mt][nt][1] + bn_);
                float v2 = gelu_f(acc[mt][nt][2] + bn_);
                float v3 = gelu_f(acc[mt][nt][3] + bn_);
                int pk = __builtin_amdgcn_cvt_pk_fp8_f32(v0, v1, 0, false);
                pk     = __builtin_amdgcn_cvt_pk_fp8_f32(v2, v3, pk, true);
                unsigned char* o = (unsigned char*)out + (size_t)m0 * N + n;
                o[0]             = (unsigned char)pk;
                o[(size_t)N]     = (unsigned char)(pk >> 8);
                o[(size_t)2 * N] = (unsigned char)(pk >> 16);
                o[(size_t)3 * N] = (unsigned char)(pk >> 24);
            } else {   // MODE 3, q/k blocks
                #pragma unroll
                for (int r = 0; r < 4; ++r) {
                    int m = bm + wm + mt * 16 + quad * 4 + r;
                    int n = bn + wn + nt * 16 + cc;
                    float v = acc[mt][nt][r] + bias[n];
                    int b_ = m >> 11, srow = m & 2047;
                    int which = n >> 10, rem = n & 1023;
                    int h = rem >> 6, d = rem & 63;
                    if (which == 0) v *= 0.125f;   // fold 1/sqrt(HD) into Q
                    size_t idx = ((((size_t)which * BATCH + b_) * NH + h) * SEQ + srow) * HD + d;
                    ((unsigned short*)out)[idx] = f2bf(v);
                }
            }
        }
}

// ---------------- fp8 NT GEMM (FC2 split-K=2): 3-buffer depth-2 counted-vmcnt pipeline ----
__global__ __launch_bounds__(256) void gemm_fp8(
        const unsigned char* __restrict__ A,
        const unsigned char* __restrict__ Bw,
        unsigned short* __restrict__ p0, unsigned short* __restrict__ p1,
        int M, int N, int K, int KC) {
    __shared__ unsigned char As[3][128 * 64];   // 3 x 8 KB
    __shared__ unsigned char Bs[3][128 * 64];   // 3 x 8 KB

    const int tid  = threadIdx.x;
    const int wave = tid >> 6;
    const int lane = tid & 63;
    const int quad = lane >> 4;
    const int cc   = lane & 15;
    const int bn = blockIdx.x * 128;
    const int bm = blockIdx.y * 128;

    const unsigned char* Ab = A  + (size_t)bm * K;
    const unsigned char* Bb = Bw + (size_t)bn * K;

    const int srow0 = tid >> 2;
    const int schunk = tid & 3;
    const int rsw = (cc >> 1) & 3;
    const int wm = (wave >> 1) * 64;
    const int wn = (wave & 1) * 64;

    const int kbeg = blockIdx.z * KC;

    f32x4 acc[4][4] = {};

    auto stage = [&](int buf, int k0) {
        #pragma unroll
        for (int i = 0; i < 2; ++i) {
            int row = i * 64 + srow0;
            int g   = schunk ^ ((row >> 1) & 3);
            const unsigned char* ga = Ab + (size_t)row * K + k0 + g * 16;
            const unsigned char* gb = Bb + (size_t)row * K + k0 + g * 16;
            unsigned char* la = &As[buf][i * 4096 + wave * 1024];
            unsigned char* lb = &Bs[buf][i * 4096 + wave * 1024];
            __builtin_amdgcn_global_load_lds((gas_t)(const void*)ga, (las_t)(void*)la, 16, 0, 0);
            __builtin_amdgcn_global_load_lds((gas_t)(const void*)gb, (las_t)(void*)lb, 16, 0, 0);
        }
    };

    const int nkt = KC >> 6;   // 32 for KC=2048
    stage(0, kbeg);
    if (nkt > 1) {
        stage(1, kbeg + 64);
        asm volatile("s_waitcnt vmcnt(4)" ::: "memory");   // buf0 landed; buf1 in flight
    } else {
        asm volatile("s_waitcnt vmcnt(0)" ::: "memory");
    }
    __builtin_amdgcn_s_barrier();

    int cur = 0;
    for (int kt = 0; kt < nkt; ++kt) {
        int pbuf = cur + 2; if (pbuf >= 3) pbuf -= 3;      // (cur+2)%3
        if (kt + 2 < nkt) stage(pbuf, kbeg + ((kt + 2) << 6));

        long af[4][2], bf[4][2];
        #pragma unroll
        for (int mt = 0; mt < 4; ++mt)
            #pragma unroll
            for (int s = 0; s < 2; ++s) {
                int slot = ((quad >> 1) + 2 * s) ^ rsw;
                af[mt][s] = *(const long*)&As[cur][(wm + mt * 16 + cc) * 64 + slot * 16 + (quad & 1) * 8];
            }
        #pragma unroll
        for (int nt = 0; nt < 4; ++nt)
            #pragma unroll
            for (int s = 0; s < 2; ++s) {
                int slot = ((quad >> 1) + 2 * s) ^ rsw;
                bf[nt][s] = *(const long*)&Bs[cur][(wn + nt * 16 + cc) * 64 + slot * 16 + (quad & 1) * 8];
            }

        #pragma unroll
        for (int mt = 0; mt < 4; ++mt)
            #pragma unroll
            for (int nt = 0; nt < 4; ++nt) {
                acc[mt][nt] = __builtin_amdgcn_mfma_f32_16x16x32_fp8_fp8(
                    af[mt][0], bf[nt][0], acc[mt][nt], 0, 0, 0);
                acc[mt][nt] = __builtin_amdgcn_mfma_f32_16x16x32_fp8_fp8(
                    af[mt][1], bf[nt][1], acc[mt][nt], 0, 0, 0);
            }

        if (kt + 1 < nkt) {
            asm volatile("s_waitcnt lgkmcnt(0)" ::: "memory");   // my LDS reads done
            if (kt + 2 < nkt)
                asm volatile("s_waitcnt vmcnt(4)" ::: "memory"); // kt+1 landed; kt+2 in flight
            else
                asm volatile("s_waitcnt vmcnt(0)" ::: "memory"); // tail: drain final tile
            __builtin_amdgcn_s_barrier();
        }
        cur = (cur < 2) ? cur + 1 : 0;
    }

    unsigned short* outp = (blockIdx.z == 0) ? p0 : p1;
    #pragma unroll
    for (int mt = 0; mt < 4; ++mt)
        #pragma unroll
        for (int nt = 0; nt < 4; ++nt)
            #pragma unroll
            for (int r = 0; r < 4; ++r) {
                int m = bm + wm + mt * 16 + quad * 4 + r;
                int n = bn + wn + nt * 16 + cc;
                outp[(size_t)m * N + n] = f2bf(acc[mt][nt][r]);
            }
}

// ---------------- MFMA flash attention v12: T14 + K/V XOR-swizzle + T5 setprio ----------
#define KPAD 72
__global__ __launch_bounds__(256, 4) void attn_mfma(
        const unsigned short* __restrict__ qkv,
        const unsigned short* __restrict__ vt,
        float* __restrict__ op0, float* __restrict__ op1,
        float* __restrict__ lpart) {
    const int tid  = threadIdx.x;
    const int wave = tid >> 6;
    const int lane = tid & 63;
    const int quad = lane >> 4;
    const int cc   = lane & 15;
    const int qblk = blockIdx.x;
    const int bh   = blockIdx.y;
    const int half = blockIdx.z;

    const size_t headsz = (size_t)SEQ * HD;
    const unsigned short* qb  = qkv + (size_t)bh * headsz;
    const unsigned short* kb  = qkv + ((size_t)BATCH * NH + bh) * headsz;
    const unsigned short* vtb = vt + (size_t)bh * headsz;
    float* opart = half ? op1 : op0;
    float* lp    = lpart + (size_t)half * BATCH * NH * SEQ;

    __shared__ unsigned short Ks[64 * 64];       // 8 KB, swizzled
    __shared__ unsigned short Vt[64 * 64];       // 8 KB, swizzled
    __shared__ unsigned short Ps[4 * 32 * KPAD]; // 18 KB, v6 layout

    bf16x8 qa[2][2];
    #pragma unroll
    for (int mt = 0; mt < 2; ++mt) {
        const unsigned short* qp =
            qb + (size_t)(qblk * 128 + wave * 32 + mt * 16 + cc) * HD + quad * 8;
        qa[mt][0] = *(const bf16x8*)qp;
        qa[mt][1] = *(const bf16x8*)(qp + 32);
    }

    f32x4 o_acc[2][4] = {};
    float l_i[2][4] = {};

    // staging geometry: 8 lanes per row, rows srow0 and srow0+8
    const int srow0 = wave * 16 + (lane >> 3);
    const int sc8c  = lane & 7;                      // logical 16B chunk
    const int swz   = (sc8c ^ (lane >> 3)) * 8;      // phys chunk offset (row&7 == lane>>3)
    const int psw   = (cc >> 2) & 3;
    const int rw7   = cc & 7;                        // fragment row & 7 for reads

    const int kt0 = half * 16, ktend = kt0 + 16;

    // prologue prefetch: named scalars (rule #20 — no arrays, no conditional defs)
    uint4 ka0, ka1, va0, va1;
    {
        const unsigned short* kp0 = &kb[(size_t)(kt0 * 64 + srow0) * HD + sc8c * 8];
        const unsigned short* vp0 = &vtb[(size_t)srow0 * SEQ + kt0 * 64 + sc8c * 8];
        ka0 = *(const uint4*)kp0;
        ka1 = *(const uint4*)(kp0 + 8 * HD);     // row srow0+8
        va0 = *(const uint4*)vp0;
        va1 = *(const uint4*)(vp0 + 8 * SEQ);    // row srow0+8
    }

    for (int kt = kt0; kt < ktend; ++kt) {
        __syncthreads();   // prev readers done
        *(uint4*)&Ks[srow0 * 64 + swz]        = ka0;
        *(uint4*)&Ks[(srow0 + 8) * 64 + swz]  = ka1;
        *(uint4*)&Vt[srow0 * 64 + swz]        = va0;
        *(uint4*)&Vt[(srow0 + 8) * 64 + swz]  = va1;
        __syncthreads();   // tile visible

        // issue next-tile loads NOW (unconditional, clamped) — hide under compute
        int ktn = (kt + 1 < ktend) ? kt + 1 : kt;
        const unsigned short* kpn = &kb[(size_t)(ktn * 64 + srow0) * HD + sc8c * 8];
        const unsigned short* vpn = &vtb[(size_t)srow0 * SEQ + ktn * 64 + sc8c * 8];
        uint4 nk0 = *(const uint4*)kpn;
        uint4 nk1 = *(const uint4*)(kpn + 8 * HD);
        uint4 nv0 = *(const uint4*)vpn;
        uint4 nv1 = *(const uint4*)(vpn + 8 * SEQ);

        f32x4 s_acc[2][4];
        __builtin_amdgcn_s_setprio(1);
        #pragma unroll
        for (int nt = 0; nt < 4; ++nt) {
            const unsigned short* kp = &Ks[(nt * 16 + cc) * 64];
            bf16x8 kf0 = *(const bf16x8*)&kp[(quad ^ rw7) * 8];
            bf16x8 kf1 = *(const bf16x8*)&kp[((quad + 4) ^ rw7) * 8];
            #pragma unroll
            for (int mt = 0; mt < 2; ++mt) {
                f32x4 z = {};
                z = __builtin_amdgcn_mfma_f32_16x16x32_bf16(qa[mt][0], kf0, z, 0, 0, 0);
                s_acc[mt][nt] = __builtin_amdgcn_mfma_f32_16x16x32_bf16(qa[mt][1], kf1, z, 0, 0, 0);
            }
        }
        __builtin_amdgcn_s_setprio(0);

        unsigned short* pw = &Ps[wave * 32 * KPAD];
        #pragma unroll
        for (int mt = 0; mt < 2; ++mt)
            #pragma unroll
            for (int nt = 0; nt < 4; ++nt) {
                int pc = ((nt ^ quad) & 3) * 16 + cc;
                #pragma unroll
                for (int r = 0; r < 4; ++r) {
                    float e = __expf(s_acc[mt][nt][r]);
                    l_i[mt][r] += e;
                    pw[(mt * 16 + quad * 4 + r) * KPAD + pc] = f2bf_up(e);
                }
            }

        bf16x8 pf[2][2];
        #pragma unroll
        for (int mt = 0; mt < 2; ++mt) {
            const unsigned short* pa = &pw[(mt * 16 + cc) * KPAD];
            pf[mt][0] = *(const bf16x8*)&pa[((((quad >> 1))     ^ psw) & 3) * 16 + (quad & 1) * 8];
            pf[mt][1] = *(const bf16x8*)&pa[(((2 + (quad >> 1)) ^ psw) & 3) * 16 + (quad & 1) * 8];
        }

        __builtin_amdgcn_s_setprio(1);
        #pragma unroll
        for (int nt = 0; nt < 4; ++nt) {
            const unsigned short* vp = &Vt[(nt * 16 + cc) * 64];
            bf16x8 vf0 = *(const bf16x8*)&vp[(quad ^ rw7) * 8];
            bf16x8 vf1 = *(const bf16x8*)&vp[((quad + 4) ^ rw7) * 8];
            #pragma unroll
            for (int mt = 0; mt < 2; ++mt) {
                o_acc[mt][nt] = __builtin_amdgcn_mfma_f32_16x16x32_bf16(
                    pf[mt][0], vf0, o_acc[mt][nt], 0, 0, 0);
                o_acc[mt][nt] = __builtin_amdgcn_mfma_f32_16x16x32_bf16(
                    pf[mt][1], vf1, o_acc[mt][nt], 0, 0, 0);
            }
        }
        __builtin_amdgcn_s_setprio(0);

        ka0 = nk0; ka1 = nk1; va0 = nv0; va1 = nv1;   // register moves
    }

    #pragma unroll
    for (int mt = 0; mt < 2; ++mt) {
        float lr[4];
        #pragma unroll
        for (int r = 0; r < 4; ++r) {
            float l = l_i[mt][r];
            #pragma unroll
            for (int off = 1; off < 16; off <<= 1)
                l += __shfl_xor(l, off, 64);
            lr[r] = l;
        }
        int rowbase = qblk * 128 + wave * 32 + mt * 16;
        if (cc == 0) {
            float4 lv = {lr[0], lr[1], lr[2], lr[3]};
            *(float4*)&lp[(size_t)bh * SEQ + rowbase + quad * 4] = lv;
        }
        #pragma unroll
        for (int nt = 0; nt < 4; ++nt)
            #pragma unroll
            for (int r = 0; r < 4; ++r) {
                int row = rowbase + quad * 4 + r;
                opart[((size_t)bh * SEQ + row) * HD + nt * 16 + cc] = o_acc[mt][nt][r];
            }
    }
}

extern "C" void kernel_launch(void* const* d_in, const int* in_sizes, int n_in,
                              void* d_out, int out_size, void* d_ws, size_t ws_size,
                              hipStream_t stream) {
    const float* src       = (const float*)d_in[0];
    const float* pre_gamma = (const float*)d_in[1];
    const float* pre_beta  = (const float*)d_in[2];
    const float* qkv_w     = (const float*)d_in[3];
    const float* qkv_b     = (const float*)d_in[4];
    const float* an_gamma  = (const float*)d_in[5];
    const float* an_beta   = (const float*)d_in[6];
    const float* fc1_w     = (const float*)d_in[7];
    const float* fc1_b     = (const float*)d_in[8];
    const float* fc2_w     = (const float*)d_in[9];
    const float* fc2_b     = (const float*)d_in[10];
    float* out = (float*)d_out;

    char* ws = (char*)d_ws;
    size_t off = 0;
    auto alloc = [&](size_t bytes) {
        char* p = ws + off;
        off += (bytes + 255) & ~(size_t)255;
        return p;
    };
    float*          x_f   = (float*)alloc((size_t)MROWS * DMODEL * 4);
    unsigned short* x_b   = (unsigned short*)alloc((size_t)MROWS * DMODEL * 2);
    float*          y_f   = (float*)alloc((size_t)MROWS * DMODEL * 4);
    unsigned short* y_b   = (unsigned short*)alloc((size_t)MROWS * DMODEL * 2);
    float*          atf   = (float*)alloc((size_t)MROWS * DMODEL * 4);
    float*          fff   = (float*)alloc((size_t)MROWS * DMODEL * 4);
    unsigned short* qkvb  = (unsigned short*)alloc((size_t)3 * MROWS * DMODEL * 2);
    unsigned char*  h8    = (unsigned char*)alloc((size_t)MROWS * FFN_DIM * 2);
    unsigned short* wqkv  = (unsigned short*)alloc((size_t)3 * DMODEL * DMODEL * 2);
    unsigned short* wfc1  = (unsigned short*)alloc((size_t)FFN_DIM * DMODEL * 2);
    unsigned char*  wfc28 = (unsigned char*)alloc((size_t)DMODEL * FFN_DIM);

    unsigned short* vt_b = (unsigned short*)fff;
    float* opart0 = atf;
    float* opart1 = (float*)h8;
    float* lpart  = (float*)x_b;
    unsigned short* fc2p0 = (unsigned short*)fff;
    unsigned short* fc2p1 = (unsigned short*)x_f;

    int n_qkv4 = 3 * DMODEL * DMODEL / 4;
    int n_fc4  = FFN_DIM * DMODEL / 4;
    int cvt_blocks = (n_qkv4 + 2 * n_fc4 + 255) / 256;

    // fused pre-LN + weight conversion (one dispatch; phases overlap)
    ln_pre_cvt<<<dim3(MROWS + cvt_blocks), dim3(256), 0, stream>>>(
        src, pre_gamma, pre_beta, x_f, x_b,
        qkv_w, wqkv, n_qkv4, fc1_w, wfc1, n_fc4, fc2_w, wfc28, n_fc4);

    // QKV GEMM (1-D XCD-swizzled grid): q/k scatter; V blocks write vt_b (fused transpose)
    gemm_lds<3><<<dim3((3 * DMODEL / 128) * (MROWS / 128)), dim3(256), 0, stream>>>(
        x_b, wqkv, qkv_b, qkvb, vt_b, MROWS, 3 * DMODEL, DMODEL);
    attn_mfma<<<dim3(SEQ / 128, BATCH * NH, 2), dim3(256), 0, stream>>>(
        qkvb, vt_b, opart0, opart1, lpart);
    ln_attn<<<dim3(MROWS), dim3(256), 0, stream>>>(
        opart0, opart1, lpart, lpart + (size_t)BATCH * NH * SEQ,
        x_f, an_gamma, an_beta, y_f, y_b);
    gemm_lds<1><<<dim3((FFN_DIM / 128) * (MROWS / 128)), dim3(256), 0, stream>>>(
        y_b, wfc1, fc1_b, h8, nullptr, MROWS, FFN_DIM, DMODEL);
    gemm_fp8<<<dim3(DMODEL / 128, MROWS / 128, 2), dim3(256), 0, stream>>>(
        h8, wfc28, fc2p0, fc2p1, MROWS, DMODEL, FFN_DIM, 2048);
    ln_fc2<<<dim3(MROWS), dim3(256), 0, stream>>>(
        fc2p0, fc2p1, fc2_b, y_f, an_gamma, an_beta, out);
}